// Round 5
// baseline (3145.764 us; speedup 1.0000x reference)
//
#include <hip/hip_runtime.h>
#include <stdint.h>

#define NPER 8192
#define NB 4
#define MPER 4096
#define MTOT (NB*MPER)      // 16384
#define KNB 64
#define CIN 64
#define R2C 0.04f           // f32-nearest of python 0.2*0.2 (NOT 0.2f*0.2f!)

// d_out (floats): x_out [MTOT*128] | pos_out [MTOT*3] | batch_out [MTOT]
#define POSOUT_OFF (MTOT*128)
#define BATCH_OFF  (MTOT*128 + MTOT*3)

// ws: nbr u16 [MTOT*64] @0 (2MB) | cnt i32 [MTOT] @2MB (64KB) |
//     precomp f32[32768*64] @PRE_OFF (8MB, optional: ws_size-gated)
#define PRE_OFF 2162688ull
#define PRE_BYTES 8388608ull

// fps->radius scratch in x_out region of d_out (free until k_conv):
// per cloud stride SSTR floats: SX[8192] @0 | SY @8192 | SZ @16384 |
// SO u16[8192] @24576f | CS u32[513] @28672f (sorted by lex cell) |
// PERM u16[8192] @29200f (brick-major pos -> lex slot, init-only) |
// WIN u16[4096] @33312f (R16: progressively published winners, 128B-aligned) |
// PROG u32 @35360f (R16: publish counter, own cache line)
#define SSTR 35392
#define PERM_F 29200
#define WIN_F 33312
#define PROG_F 35360

#define NCONS 248           // consumer blocks; 248+4 <= 256 CUs at 1 blk/CU
                            // => producers get CUs under ANY dispatch order
#define SCAP 512

typedef float v2f __attribute__((ext_vector_type(2)));

// ---------------------------------------------------------------- K1 fused
// R10/R12-proven exact lazy FPS. LOOP AND CONFIG FROZEN: 0 wins in 5
// attempts touching it (R5/R9/R11 reduce edits regressed; R12 ownership
// NULL; R13 8x16 +44% — passing-wave serial update is the critical path).
// R14/R15: k_pre fused as extra blocks — banked −94us (also clock-ramp:
// fused FPS runs 2400 vs 2516 standalone).
// R16: k_radius STREAMED into the FPS shadow as persistent consumer blocks
// in the same dispatch. Producer publishes winb in 256-entry chunks
// (tid<128 copy -> syncthreads -> threadfence -> agent atomic store of
// PROG); consumers (248 blocks x 16 waves, one centroid/wave/group) spin
// on PROG (wave0 polls w/ s_sleep, others park on barrier), acquire, then
// run the EXACT k_radius code with coords via published slot (bitwise ==
// old qo read). Deadlock-safe by construction: 248+4 <= 256 CUs at 1
// block/CU (uniform 129KB dynamic LDS), pre blocks retire unconditionally,
// conv2 stays a separate dispatch. k_zero resets PROG each launch
// (poison/replay-safe).
#define FPS_T 1024
#define PTS 8
#define NCELL 512

// dynamic-LDS layout (bytes)
#define OFF_XS 0
#define OFF_YS (OFF_XS + NPER*4)        // 32768
#define OFF_ZS (OFF_YS + NPER*4)        // 65536
#define OFF_OS (OFF_ZS + NPER*4)        // 98304  u16[8192]
#define OFF_WIN (OFF_OS + NPER*2)       // 114688 u16[4096]
#define OFF_HIST (OFF_WIN + MPER*2)     // 122880 u32[512]
#define OFF_SCAN (OFF_HIST + NCELL*4)   // 124928 u32[512]
#define OFF_SLOT (OFF_SCAN + NCELL*4)   // 126976 u64[3]
#define OFF_SID0 (OFF_SLOT + 24)        // 127000 u32
#define OFF_BSC  (OFF_SID0 + 8)         // 127008 u32[512] (brick scan)
#define FPS_LDS  (OFF_BSC + NCELL*4)    // 129056 B

template<int CTRL>
__device__ __forceinline__ unsigned dppmax(unsigned v) {
  unsigned t = (unsigned)__builtin_amdgcn_update_dpp(
      0, (int)v, CTRL, 0xf, 0xf, true);   // bound_ctrl: OOB lanes read 0
  return v > t ? v : t;
}
__device__ __forceinline__ unsigned wave_max_u32(unsigned v) {
  v = dppmax<0x111>(v);   // row_shr:1
  v = dppmax<0x112>(v);   // row_shr:2
  v = dppmax<0x114>(v);   // row_shr:4
  v = dppmax<0x118>(v);   // row_shr:8
  v = dppmax<0x142>(v);   // row_bcast15
  v = dppmax<0x143>(v);   // row_bcast31
  return (unsigned)__builtin_amdgcn_readlane((int)v, 63);
}

// brick-major cell index: brick = 4x4x2 cells (0.5 x 0.5 x 0.25), 16 bricks
// == 16 waves; bijection over [0,512).
__device__ __forceinline__ unsigned brick_key(unsigned c) {
  unsigned ix = c >> 6, iy = (c >> 3) & 7, iz = c & 7;
  unsigned bid = ((ix >> 2) << 3) | ((iy >> 2) << 2) | (iz >> 1);
  unsigned lid = ((ix & 3) << 3) | ((iy & 3) << 1) | (iz & 1);
  return (bid << 5) | lid;
}

// R16: reset publish counters (stream-ordered before the fused dispatch;
// poison- and graph-replay-safe).
__global__ void k_zero(float* __restrict__ dout) {
  int t = threadIdx.x;
  if (t < NB) *(unsigned*)(dout + (size_t)t * SSTR + PROG_F) = 0u;
}

__global__ __launch_bounds__(1024) void k_fps(const float* __restrict__ pos,
                                              float* __restrict__ dout,
                                              const float* __restrict__ xin,
                                              const float* __restrict__ W1,
                                              float* __restrict__ hp,
                                              unsigned short* __restrict__ nbr,
                                              int* __restrict__ cnt,
                                              int cbase)
{
#pragma clang fp contract(off)
  extern __shared__ char smem[];
  const int tid = threadIdx.x;

  // ---- fused k_pre blocks: hp = x @ W1[:64], bitwise == old k_pre.
  if (blockIdx.x >= NB && (int)blockIdx.x < cbase) {
    float* Ws = (float*)smem;                    // [64*64] ch-major
    float* Xs2 = (float*)(smem + 16384);         // [64][65]
    const int row0 = (blockIdx.x - NB) * 64;
    for (int e = tid; e < 64*64; e += FPS_T) Ws[e] = W1[e];
    for (int e = tid; e < 64*64; e += FPS_T) {
      int r = e >> 6, ch = e & 63;
      Xs2[r*65 + ch] = xin[(size_t)(row0 + r) * 64 + ch];
    }
    __syncthreads();                             // all 16 waves participate
    if (tid < 256) {
      const int rg = tid >> 4, cg = tid & 15;
      const int r0 = rg << 2, c0 = cg << 2;
      float acc[4][4];
#pragma unroll
      for (int r = 0; r < 4; ++r)
#pragma unroll
        for (int c = 0; c < 4; ++c) acc[r][c] = 0.0f;
      for (int k = 0; k < 64; ++k) {
        const float4 w = *(const float4*)&Ws[(k << 6) + c0];
        const float xr[4] = {Xs2[(r0+0)*65 + k], Xs2[(r0+1)*65 + k],
                             Xs2[(r0+2)*65 + k], Xs2[(r0+3)*65 + k]};
        const float wc[4] = {w.x, w.y, w.z, w.w};
#pragma unroll
        for (int r = 0; r < 4; ++r)
#pragma unroll
          for (int c = 0; c < 4; ++c)
            acc[r][c] = fmaf(xr[r], wc[c], acc[r][c]);
      }
#pragma unroll
      for (int r = 0; r < 4; ++r) {
        float4 o = {acc[r][0], acc[r][1], acc[r][2], acc[r][3]};
        *(float4*)&hp[(size_t)(row0 + r0 + r) * 64 + c0] = o;
      }
    }
    return;
  }

  // ---- R16: radius consumers (persistent; blocks >= cbase) ----
  // Exact port of the proven k_radius; coords via published slot
  // (gSX[slot] bitwise == old qo read). One centroid per wave per group.
  if ((int)blockIdx.x >= cbase) {
    unsigned* candH = (unsigned*)smem;              // [16][SCAP]
    unsigned* candL = candH + 16*SCAP;              // [16][SCAP]
    const int wid = tid >> 6, lane = tid & 63;
    const int cb0 = (int)blockIdx.x - cbase;
    for (int g = cb0; g < MTOT/16; g += NCONS) {
      const int m = g*16 + wid;
      const int b = m >> 12;
      const float* scrb2 = dout + (size_t)b * SSTR;
      unsigned* progp = (unsigned*)(scrb2 + PROG_F);
      const unsigned blkmax = (unsigned)((g*16 + 15) & 4095) + 1u;
      if (wid == 0) {                 // wave-uniform poll; others park @bar
        unsigned v;
        do {
          unsigned t0 = 0u;
          if (lane == 0)
            t0 = __hip_atomic_load(progp, __ATOMIC_RELAXED,
                                   __HIP_MEMORY_SCOPE_AGENT);
          v = (unsigned)__builtin_amdgcn_readfirstlane((int)t0);
          if (v < blkmax) __builtin_amdgcn_s_sleep(32);
        } while (v < blkmax);
      }
      __syncthreads();
      (void)__hip_atomic_load(progp, __ATOMIC_ACQUIRE,
                              __HIP_MEMORY_SCOPE_AGENT);  // inv stale L1/L2
      const float* SX = scrb2;
      const float* SY = scrb2 + 8192;
      const float* SZ = scrb2 + 16384;
      const unsigned short* SO = (const unsigned short*)(scrb2 + 24576);
      const unsigned* CS = (const unsigned*)(scrb2 + 28672);
      const unsigned short* gWIN = (const unsigned short*)(scrb2 + WIN_F);
      const unsigned slot = gWIN[m & 4095];
      const float qx = SX[slot], qy = SY[slot], qz = SZ[slot];
      const int ixc = min(7, (int)(qx * 8.0f));
      const int iyc = min(7, (int)(qy * 8.0f));
      const int izc = min(7, (int)(qz * 8.0f));
      const int izlo = max(izc-2, 0), izhi = min(izc+2, 7);
      unsigned s0v = 0u, s1v = 0u;
      {
        int ix = ixc + lane / 5 - 2;
        int iy = iyc + lane % 5 - 2;
        if (lane < 25 && ix >= 0 && ix < 8 && iy >= 0 && iy < 8) {
          int cbq = (ix << 6) | (iy << 3);
          s0v = CS[cbq + izlo];
          s1v = CS[cbq + izhi + 1];
        }
      }
      unsigned cw = 0;
      for (int seg = 0; seg < 25; ++seg) {
        unsigned s0 = (unsigned)__builtin_amdgcn_readlane((int)s0v, seg);
        unsigned s1 = (unsigned)__builtin_amdgcn_readlane((int)s1v, seg);
        for (unsigned i0 = s0; i0 < s1; i0 += 64) {
          unsigned i = i0 + (unsigned)lane;   // OOB lanes read harmless bytes
          float dx = __fsub_rn(qx, SX[i]);
          float dy = __fsub_rn(qy, SY[i]);
          float dz = __fsub_rn(qz, SZ[i]);
          float d2 = __fadd_rn(__fadd_rn(__fmul_rn(dx,dx), __fmul_rn(dy,dy)),
                               __fmul_rn(dz,dz));
          bool in = (i < s1) && (d2 <= R2C);
          unsigned long long mk = __ballot(in);
          unsigned pre = (unsigned)__popcll(mk & ((1ull << lane) - 1ull));
          if (in) {
            unsigned slt = cw + pre;
            if (slt < SCAP) {
              candH[wid*SCAP + slt] = __float_as_uint(d2);
              candL[wid*SCAP + slt] = (unsigned)SO[i];
            }
          }
          cw += (unsigned)__popcll(mk);
        }
      }
      if (cw > SCAP) cw = SCAP;
      for (int s = (int)cw + lane; s < SCAP; s += 64) {
        candH[wid*SCAP + s] = 0xFFFFFFFFu; candL[wid*SCAP + s] = 0xFFFFFFFFu;
      }
      __syncthreads();
      for (int k = 2; k <= SCAP; k <<= 1) {
        for (int j = k >> 1; j > 0; j >>= 1) {
#pragma unroll
          for (int s = 0; s < SCAP/128; ++s) {
            int t = lane + (s << 6);
            int e = ((t & ~(j-1)) << 1) | (t & (j-1));
            int p = e | j;
            unsigned aH = candH[wid*SCAP + e], aL = candL[wid*SCAP + e];
            unsigned cH = candH[wid*SCAP + p], cL = candL[wid*SCAP + p];
            bool agt = (aH > cH) || (aH == cH && aL > cL);
            bool asc = ((e & k) == 0);
            bool sw = asc ? agt : !agt && (aH != cH || aL != cL);
            if (sw) {
              candH[wid*SCAP + e] = cH; candL[wid*SCAP + e] = cL;
              candH[wid*SCAP + p] = aH; candL[wid*SCAP + p] = aL;
            }
          }
          __syncthreads();
        }
      }
      int kk = (int)cw; if (kk > KNB) kk = KNB;
      nbr[(size_t)m*KNB + lane] =
        (lane < kk) ? (unsigned short)(candL[wid*SCAP + lane] & 0xFFFFu)
                    : (unsigned short)0;
      if (lane == 0) {
        cnt[m] = kk;
        dout[BATCH_OFF + m] = (float)b;   // batch_out
      }
      __syncthreads();                    // re-align block before next group
    }
    return;
  }

  // ---- FPS producer blocks (0..NB-1) ----
  float* Xs = (float*)(smem + OFF_XS);
  float* Ys = (float*)(smem + OFF_YS);
  float* Zs = (float*)(smem + OFF_ZS);
  unsigned short* Os = (unsigned short*)(smem + OFF_OS);
  unsigned short* winb = (unsigned short*)(smem + OFF_WIN);
  unsigned* hist = (unsigned*)(smem + OFF_HIST);
  unsigned* scanb = (unsigned*)(smem + OFF_SCAN);
  unsigned long long* slot3 = (unsigned long long*)(smem + OFF_SLOT);
  unsigned* sid0p = (unsigned*)(smem + OFF_SID0);
  unsigned* bsc = (unsigned*)(smem + OFF_BSC);

  const int b = blockIdx.x;
  const float* pb = pos + (size_t)b * NPER * 3;
  float* qo = dout + POSOUT_OFF + (size_t)b * MPER * 3;
  float* scrb = dout + (size_t)b * SSTR;
  float* gSX = scrb; float* gSY = scrb + 8192; float* gSZ = scrb + 16384;
  unsigned* gSO = (unsigned*)(scrb + 24576);       // packed u16 pairs
  unsigned* gCS = (unsigned*)(scrb + 28672);       // 513 entries
  unsigned short* gPM = (unsigned short*)(scrb + PERM_F);  // perm
  unsigned* gWINu32 = (unsigned*)(scrb + WIN_F);   // R16 publish target
  unsigned* winbU32 = (unsigned*)winb;
  unsigned* progp = (unsigned*)(scrb + PROG_F);

  if (tid < NCELL) hist[tid] = 0u;
  if (tid == 0) { slot3[0] = 0ull; slot3[1] = 0ull; slot3[2] = 0ull; }
  __syncthreads();

  // ---- sort pass 1: count (lex cell) ----
  float sxv[PTS], syv[PTS], szv[PTS];
  unsigned cellv[PTS];
#pragma unroll
  for (int k = 0; k < PTS; ++k) {
    int i = k * FPS_T + tid;
    sxv[k] = pb[i*3+0]; syv[k] = pb[i*3+1]; szv[k] = pb[i*3+2];
    unsigned ix = min(7u, (unsigned)(int)(sxv[k] * 8.0f));
    unsigned iy = min(7u, (unsigned)(int)(syv[k] * 8.0f));
    unsigned iz = min(7u, (unsigned)(int)(szv[k] * 8.0f));
    cellv[k] = (ix << 6) | (iy << 3) | iz;
    atomicAdd(&hist[cellv[k]], 1u);
  }
  __syncthreads();
  // ---- scan -> exclusive starts; export CS to global ----
  if (tid < NCELL) scanb[tid] = hist[tid];
  __syncthreads();
  for (int s = 1; s < NCELL; s <<= 1) {
    unsigned v = 0u;
    if (tid >= s && tid < NCELL) v = scanb[tid - s];
    __syncthreads();
    if (tid >= s && tid < NCELL) scanb[tid] += v;
    __syncthreads();
  }
  if (tid < NCELL) {
    hist[tid] = scanb[tid] - hist[tid];   // exclusive start
    gCS[tid+1] = scanb[tid];              // start of cell tid+1
  }
  if (tid == 0) gCS[0] = 0u;
  __syncthreads();
  // ---- brick-order scan (wave-compact ownership) ----
  if (tid < NCELL) {
    unsigned c = (unsigned)tid;
    unsigned cntc = scanb[c] - hist[c];
    bsc[brick_key(c)] = cntc;             // counts in brick-major order
  }
  __syncthreads();
  for (int s = 1; s < NCELL; s <<= 1) {
    unsigned v = 0u;
    if (tid >= s && tid < NCELL) v = bsc[tid - s];
    __syncthreads();
    if (tid >= s && tid < NCELL) bsc[tid] += v;
    __syncthreads();
  }
  {
    unsigned bst = 0u;
    if (tid < NCELL) {
      unsigned c = (unsigned)tid;
      unsigned cntc = scanb[c] - hist[c];
      bst = bsc[brick_key(c)] - cntc;     // brick-order exclusive start
    }
    __syncthreads();
    if (tid < NCELL) bsc[tid] = bst;      // re-index by CELL: pass-2 counters
  }
  __syncthreads();
  // ---- sort pass 2: scatter into LDS (lex) + perm (brick-major) ----
#pragma unroll
  for (int k = 0; k < PTS; ++k) {
    unsigned dst = atomicAdd(&hist[cellv[k]], 1u);
    unsigned p   = atomicAdd(&bsc[cellv[k]], 1u);
    int orig = k * FPS_T + tid;
    Xs[dst] = sxv[k]; Ys[dst] = syv[k]; Zs[dst] = szv[k];
    Os[dst] = (unsigned short)orig;
    gPM[p] = (unsigned short)dst;         // brick pos p -> lex slot dst
    if (orig == 0) *sid0p = dst;
  }
  __syncthreads();
  // ---- dump sorted cloud to global scratch (for consumers) ----
  for (int e = tid; e < NPER; e += FPS_T) {
    gSX[e] = Xs[e]; gSY[e] = Ys[e]; gSZ[e] = Zs[e];
  }
  for (int e = tid; e < NPER/2; e += FPS_T)
    gSO[e] = ((const unsigned*)Os)[e];
  // ---- own 8 brick-contiguous points (via perm) + AABB ----
  v2f Xp[4], Yp[4], Zp[4], Dp[4];
  unsigned RK[PTS];
  float bxlo = 3.402823466e+38f, bylo = bxlo, bzlo = bxlo;
  float bxhi = -bxlo, byhi = bxhi, bzhi = bxhi;
#pragma unroll
  for (int k = 0; k < PTS; ++k) {
    int s = (int)gPM[tid * PTS + k];
    float xx = Xs[s], yy = Ys[s], zz = Zs[s];
    Xp[k>>1][k&1] = xx; Yp[k>>1][k&1] = yy; Zp[k>>1][k&1] = zz;
    Dp[k>>1][k&1] = 3.402823466e+38f;
    unsigned orig = Os[s];
    RK[k] = ((unsigned)(NPER - 1 - orig) << 13) | (unsigned)s;
    bxlo = fminf(bxlo, xx); bxhi = fmaxf(bxhi, xx);
    bylo = fminf(bylo, yy); byhi = fmaxf(byhi, yy);
    bzlo = fminf(bzlo, zz); bzhi = fmaxf(bzhi, zz);
  }

  // ---- main loop (hot path UNCHANGED — R10-proven; FROZEN). R16 adds a
  // publish block on 15 of 4095 iterations ((m&255)==1, m>256): flush the
  // completed 256-entry winb chunk + release-store PROG. ----
  unsigned long long tkey = 0ull, wkey = 0ull;
  float lmax = 3.402823466e+38f;
  unsigned sidx = *sid0p;
  for (int m = 1; m < MPER; ++m) {
    const float cx = Xs[sidx], cy = Ys[sidx], cz = Zs[sidx];  // broadcasts
    if (tid == 0) winb[m-1] = (unsigned short)sidx;
    if (tid == 1) slot3[(m+1) % 3] = 0ull;   // phase-safe future reset
    if ((m & 255) == 1 && m > 256) {         // R16 publish (15x total)
      const int u0 = ((m - 257) >> 8) << 7;  // u32 base of chunk
      if (tid < 128) gWINu32[u0 + tid] = winbU32[u0 + tid];
      __syncthreads();
      if (tid == 0) {
        __threadfence();
        __hip_atomic_store(progp, (unsigned)(m - 1), __ATOMIC_RELAXED,
                           __HIP_MEMORY_SCOPE_AGENT);
      }
    }
    float ax = fmaxf(fmaxf(__fsub_rn(bxlo, cx), __fsub_rn(cx, bxhi)), 0.0f);
    float ay = fmaxf(fmaxf(__fsub_rn(bylo, cy), __fsub_rn(cy, byhi)), 0.0f);
    float az = fmaxf(fmaxf(__fsub_rn(bzlo, cz), __fsub_rn(cz, bzhi)), 0.0f);
    float lb = ax*ax + ay*ay + az*az;
    bool upd = (lb * 0.99988f) < lmax;  // margin >> rounding: skip is exact
    if (__ballot(upd) != 0ull) {        // whole wave can skip
      if (upd) {
        v2f cx2 = {cx, cx}, cy2 = {cy, cy}, cz2 = {cz, cz};
        v2f dnp[4];
        float bd = -1.0f;
#pragma unroll
        for (int p = 0; p < 4; ++p) {
          v2f dx = Xp[p] - cx2;
          v2f dy = Yp[p] - cy2;
          v2f dz = Zp[p] - cz2;
          v2f s = (dx*dx + dy*dy) + dz*dz;   // rn, no fma (contract off)
          v2f dn;
          dn.x = fminf(Dp[p].x, s.x);
          dn.y = fminf(Dp[p].y, s.y);
          Dp[p] = dn; dnp[p] = dn;
          bd = fmaxf(bd, fmaxf(dn.x, dn.y));
        }
        unsigned brk = 0u;
#pragma unroll
        for (int p = 0; p < 4; ++p) {
          brk = (dnp[p].x == bd) ? max(brk, RK[2*p])   : brk;
          brk = (dnp[p].y == bd) ? max(brk, RK[2*p+1]) : brk;
        }
        tkey = ((unsigned long long)__float_as_uint(bd) << 26) | brk;
        lmax = bd;
      }
      unsigned hi = (unsigned)(tkey >> 26);
      unsigned M = wave_max_u32(hi);
      unsigned rk = (unsigned)tkey & 0x3FFFFFFu;
      unsigned long long msk = __ballot(hi == M);
      unsigned lo;
      if (__popcll(msk) == 1) {          // sole owner (the ~always case)
        int ln = (int)__builtin_ctzll(msk);
        lo = (unsigned)__builtin_amdgcn_readlane((int)rk, ln);
      } else {                           // exact d2 tie: max RK = min orig
        lo = wave_max_u32((hi == M) ? rk : 0u);
      }
      wkey = ((unsigned long long)M << 26) | lo;
    }
    if ((tid & 63) == 0) atomicMax(&slot3[m % 3], wkey);
    __syncthreads();
    sidx = (unsigned)(slot3[m % 3] & 0x1FFFull);
  }
  if (tid == 0) winb[MPER-1] = (unsigned short)sidx;
  __syncthreads();
  // reconstruct pos_out from LDS
  for (int e = tid; e < MPER; e += FPS_T) {
    unsigned s = winb[e];
    qo[e*3+0] = Xs[s]; qo[e*3+1] = Ys[s]; qo[e*3+2] = Zs[s];
  }
  // ---- R16: final publish (entries 3840..4095) ----
  if (tid < 128) gWINu32[1920 + tid] = winbU32[1920 + tid];
  __syncthreads();
  if (tid == 0) {
    __threadfence();
    __hip_atomic_store(progp, 4096u, __ATOMIC_RELAXED,
                       __HIP_MEMORY_SCOPE_AGENT);
  }
}

// ---------------------------------- K3a: conv using precomp (ws-size gated)
// Gather hp rows (h1 partial sums) -> h1T in LDS; fuse rel@W1[64:67] + b1 +
// relu (fmaf order 64,65,66 then +b1: bitwise == legacy); stage2 packed
// v_pk_fma. LDS ~28KB.
__global__ __launch_bounds__(128) void k_conv2(
    const float* __restrict__ hp, const float* __restrict__ pos,
    const float* __restrict__ W1, const float* __restrict__ b1,
    const float* __restrict__ W2, const float* __restrict__ b2,
    const unsigned short* __restrict__ nbr, const int* __restrict__ cntp,
    float* __restrict__ dout)
{
  __shared__ __align__(16) float bufA[68*68];   // h1T rows 0..63, relT 64..66
  __shared__ __align__(16) float bufB[16*136];  // W2 chunk (stride 136)
  __shared__ float w1p[3*64];
  __shared__ unsigned short nbr_s[64];
  __shared__ float qv[3];
  __shared__ int cnt_s;
  const int t = threadIdx.x;
  const int m = blockIdx.x;
  const int b = m >> 12;
  if (t < 64) nbr_s[t] = nbr[(size_t)m*KNB + t];
  else if (t == 64) cnt_s = cntp[m];
  else if (t >= 65 && t < 68) qv[t-65] = dout[POSOUT_OFF + (size_t)m*3 + (t-65)];
  for (int e = t; e < 192; e += 128) w1p[e] = W1[64*64 + e];
  __syncthreads();
  {                                   // gather hp rows -> h1T rows 0..63
    const int h = t & 63, jj = t >> 6;
    const size_t hb = (size_t)b * NPER * 64;
    for (int j0 = 0; j0 < 64; j0 += 2) {
      int j = j0 + jj;
      int r = nbr_s[j];
      bufA[h*68 + j] = hp[hb + (size_t)r*64 + h];
    }
  }
  {                                   // rel -> rows 64..66
    const size_t pbb = (size_t)b * NPER * 3;
    for (int e = t; e < 192; e += 128) {
      int j = e & 63, d = e >> 6;
      int r = nbr_s[j];
      bufA[(64+d)*68 + j] = pos[pbb + (size_t)r*3 + d] - qv[d];
    }
  }
  __syncthreads();
  // fuse: h1T[h][j] = relu(h1T + rel@w1p + b1)  (fmaf order 64,65,66, +b1)
  for (int e = t; e < 64*64; e += 128) {
    int h = e >> 6, j = e & 63;
    float v = bufA[h*68 + j];
    v = fmaf(bufA[64*68 + j], w1p[h],       v);
    v = fmaf(bufA[65*68 + j], w1p[64 + h],  v);
    v = fmaf(bufA[66*68 + j], w1p[128 + h], v);
    bufA[h*68 + j] = fmaxf(v + b1[h], 0.0f);
  }
  const int jg = t & 7, hg = t >> 3;
  const int j0 = jg << 3;
  const int c0 = hg << 3;             // stage2: 8j x 8c packed pairs
  v2f acc2p[8][4];                    // [c][jpair]
#pragma unroll
  for (int c = 0; c < 8; ++c)
#pragma unroll
    for (int jp = 0; jp < 4; ++jp) acc2p[c][jp] = (v2f){0.0f, 0.0f};
  for (int hc = 0; hc < 64; hc += 16) {
    __syncthreads();                  // h1T ready / prior chunk consumed
    for (int e = t; e < 16*128; e += 128) {
      int hh = e >> 7, c = e & 127;
      bufB[hh*136 + c] = W2[(size_t)(hc+hh)*128 + c];
    }
    __syncthreads();
#pragma unroll
    for (int h = 0; h < 16; ++h) {
      const float4 ja = *(const float4*)&bufA[(hc+h)*68 + j0];
      const float4 jb = *(const float4*)&bufA[(hc+h)*68 + j0 + 4];
      const float4 wa = *(const float4*)&bufB[h*136 + c0];
      const float4 wb = *(const float4*)&bufB[h*136 + c0 + 4];
      const v2f hj[4] = {{ja.x, ja.y}, {ja.z, ja.w}, {jb.x, jb.y}, {jb.z, jb.w}};
      const float wv[8] = {wa.x, wa.y, wa.z, wa.w, wb.x, wb.y, wb.z, wb.w};
#pragma unroll
      for (int c = 0; c < 8; ++c) {
        const v2f w2 = {wv[c], wv[c]};
#pragma unroll
        for (int jp = 0; jp < 4; ++jp)
          acc2p[c][jp] += w2 * hj[jp];          // v_pk_fma_f32
      }
    }
  }
  const int cntv = cnt_s;
  const float4 b2a = *(const float4*)&b2[c0];
  const float4 b2b = *(const float4*)&b2[c0 + 4];
  const float bv2[8] = {b2a.x, b2a.y, b2a.z, b2a.w, b2b.x, b2b.y, b2b.z, b2b.w};
  float best[8];
#pragma unroll
  for (int c = 0; c < 8; ++c) {
    float v = -3.402823466e+38f;
#pragma unroll
    for (int jp = 0; jp < 4; ++jp) {
      float h0v = fmaxf(acc2p[c][jp].x + bv2[c], 0.0f);
      float h1v = fmaxf(acc2p[c][jp].y + bv2[c], 0.0f);
      v = (j0 + 2*jp     < cntv) ? fmaxf(v, h0v) : v;
      v = (j0 + 2*jp + 1 < cntv) ? fmaxf(v, h1v) : v;
    }
    best[c] = v;
  }
#pragma unroll
  for (int off = 1; off < 8; off <<= 1)
#pragma unroll
    for (int c = 0; c < 8; ++c)
      best[c] = fmaxf(best[c], __shfl_xor(best[c], off));
  if (jg == 0) {
    float4 o0 = {best[0], best[1], best[2], best[3]};
    float4 o1 = {best[4], best[5], best[6], best[7]};
    *(float4*)&dout[(size_t)m*128 + c0] = o0;
    *(float4*)&dout[(size_t)m*128 + c0 + 4] = o1;
  }
}

// --------------------------------------------- K3b: legacy conv (fallback)
__global__ __launch_bounds__(128) void k_conv(
    const float* __restrict__ x, const float* __restrict__ pos,
    const float* __restrict__ W1, const float* __restrict__ b1,
    const float* __restrict__ W2, const float* __restrict__ b2,
    const unsigned short* __restrict__ nbr, const int* __restrict__ cntp,
    float* __restrict__ dout)
{
  __shared__ __align__(16) float bufA[68*68];
  __shared__ __align__(16) float bufB[68*68];
  __shared__ unsigned short nbr_s[64];
  __shared__ float qv[3];
  __shared__ int cnt_s;
  const int t = threadIdx.x;
  const int m = blockIdx.x;
  const int b = m >> 12;
  if (t < 64) nbr_s[t] = nbr[(size_t)m*KNB + t];
  else if (t == 64) cnt_s = cntp[m];
  else if (t >= 65 && t < 68) qv[t-65] = dout[POSOUT_OFF + (size_t)m*3 + (t-65)];
  for (int e = t; e < 67*64; e += 128) {
    int ch = e >> 6, h = e & 63;
    bufB[ch*68 + h] = W1[e];
  }
  __syncthreads();
  {
    const int ch = t & 63, jj = t >> 6;
    const size_t xb = (size_t)b * NPER * CIN;
    for (int j0 = 0; j0 < 64; j0 += 2) {
      int j = j0 + jj;
      int r = nbr_s[j];
      bufA[ch*68 + j] = x[xb + (size_t)r*CIN + ch];
    }
  }
  {
    const size_t pbb = (size_t)b * NPER * 3;
    for (int e = t; e < 192; e += 128) {
      int j = e & 63, d = e >> 6;
      int r = nbr_s[j];
      bufA[(64+d)*68 + j] = pos[pbb + (size_t)r*3 + d] - qv[d];
    }
  }
  __syncthreads();
  const int jg = t & 7, hg = t >> 3;
  const int j0 = jg << 3;
  const int h0 = hg << 2;
  v2f accp[4][4];
#pragma unroll
  for (int hh = 0; hh < 4; ++hh)
#pragma unroll
    for (int jp = 0; jp < 4; ++jp) accp[hh][jp] = (v2f){0.0f, 0.0f};
  for (int ch = 0; ch < 67; ++ch) {
    const float4 fa = *(const float4*)&bufA[ch*68 + j0];
    const float4 fb = *(const float4*)&bufA[ch*68 + j0 + 4];
    const float4 w  = *(const float4*)&bufB[ch*68 + h0];
    const v2f fj[4] = {{fa.x, fa.y}, {fa.z, fa.w}, {fb.x, fb.y}, {fb.z, fb.w}};
    const float ws4[4] = {w.x, w.y, w.z, w.w};
#pragma unroll
    for (int hh = 0; hh < 4; ++hh) {
      const v2f wv2 = {ws4[hh], ws4[hh]};
#pragma unroll
      for (int jp = 0; jp < 4; ++jp)
        accp[hh][jp] += wv2 * fj[jp];
    }
  }
  __syncthreads();
  {
    const float4 bb = *(const float4*)&b1[h0];
    const float bv[4] = {bb.x, bb.y, bb.z, bb.w};
#pragma unroll
    for (int hh = 0; hh < 4; ++hh) {
      float4 o0, o1;
      o0.x = fmaxf(accp[hh][0].x + bv[hh], 0.0f);
      o0.y = fmaxf(accp[hh][0].y + bv[hh], 0.0f);
      o0.z = fmaxf(accp[hh][1].x + bv[hh], 0.0f);
      o0.w = fmaxf(accp[hh][1].y + bv[hh], 0.0f);
      o1.x = fmaxf(accp[hh][2].x + bv[hh], 0.0f);
      o1.y = fmaxf(accp[hh][2].y + bv[hh], 0.0f);
      o1.z = fmaxf(accp[hh][3].x + bv[hh], 0.0f);
      o1.w = fmaxf(accp[hh][3].y + bv[hh], 0.0f);
      *(float4*)&bufA[(h0+hh)*68 + j0] = o0;
      *(float4*)&bufA[(h0+hh)*68 + j0 + 4] = o1;
    }
  }
  const int c0 = hg << 3;
  v2f acc2p[8][4];
#pragma unroll
  for (int c = 0; c < 8; ++c)
#pragma unroll
    for (int jp = 0; jp < 4; ++jp) acc2p[c][jp] = (v2f){0.0f, 0.0f};
  for (int hc = 0; hc < 64; hc += 16) {
    __syncthreads();
    for (int e = t; e < 16*128; e += 128) {
      int hh = e >> 7, c = e & 127;
      bufB[hh*136 + c] = W2[(size_t)(hc+hh)*128 + c];
    }
    __syncthreads();
#pragma unroll
    for (int h = 0; h < 16; ++h) {
      const float4 ja = *(const float4*)&bufA[(hc+h)*68 + j0];
      const float4 jb = *(const float4*)&bufA[(hc+h)*68 + j0 + 4];
      const float4 wa = *(const float4*)&bufB[h*136 + c0];
      const float4 wb = *(const float4*)&bufB[h*136 + c0 + 4];
      const v2f hj[4] = {{ja.x, ja.y}, {ja.z, ja.w}, {jb.x, jb.y}, {jb.z, jb.w}};
      const float wv[8] = {wa.x, wa.y, wa.z, wa.w, wb.x, wb.y, wb.z, wb.w};
#pragma unroll
      for (int c = 0; c < 8; ++c) {
        const v2f w2 = {wv[c], wv[c]};
#pragma unroll
        for (int jp = 0; jp < 4; ++jp)
          acc2p[c][jp] += w2 * hj[jp];
      }
    }
  }
  const int cntv = cnt_s;
  const float4 b2a = *(const float4*)&b2[c0];
  const float4 b2b = *(const float4*)&b2[c0 + 4];
  const float bv2[8] = {b2a.x, b2a.y, b2a.z, b2a.w, b2b.x, b2b.y, b2b.z, b2b.w};
  float best[8];
#pragma unroll
  for (int c = 0; c < 8; ++c) {
    float v = -3.402823466e+38f;
#pragma unroll
    for (int jp = 0; jp < 4; ++jp) {
      float h0v = fmaxf(acc2p[c][jp].x + bv2[c], 0.0f);
      float h1v = fmaxf(acc2p[c][jp].y + bv2[c], 0.0f);
      v = (j0 + 2*jp     < cntv) ? fmaxf(v, h0v) : v;
      v = (j0 + 2*jp + 1 < cntv) ? fmaxf(v, h1v) : v;
    }
    best[c] = v;
  }
#pragma unroll
  for (int off = 1; off < 8; off <<= 1)
#pragma unroll
    for (int c = 0; c < 8; ++c)
      best[c] = fmaxf(best[c], __shfl_xor(best[c], off));
  if (jg == 0) {
    float4 o0 = {best[0], best[1], best[2], best[3]};
    float4 o1 = {best[4], best[5], best[6], best[7]};
    *(float4*)&dout[(size_t)m*128 + c0] = o0;
    *(float4*)&dout[(size_t)m*128 + c0 + 4] = o1;
  }
}

extern "C" void kernel_launch(void* const* d_in, const int* in_sizes, int n_in,
                              void* d_out, int out_size, void* d_ws, size_t ws_size,
                              hipStream_t stream) {
  const float* x   = (const float*)d_in[0];
  const float* pos = (const float*)d_in[1];
  // d_in[2] = batch (layout known statically, unused)
  const float* W1  = (const float*)d_in[3];
  const float* b1  = (const float*)d_in[4];
  const float* W2  = (const float*)d_in[5];
  const float* b2  = (const float*)d_in[6];
  float* dout = (float*)d_out;
  unsigned short* nbr = (unsigned short*)d_ws;
  int* cnt = (int*)((char*)d_ws + (size_t)MTOT*KNB*2);
  float* hp = (float*)((char*)d_ws + PRE_OFF);
  const bool use_pre = (ws_size >= PRE_OFF + PRE_BYTES);  // constant per run

  // R16: one fused dispatch = FPS producers (blocks 0..3) + pre GEMM
  // (4..cbase-1) + persistent radius consumers (cbase..cbase+NCONS-1).
  // k_zero resets the publish counters first (stream-ordered).
  const int cbase = use_pre ? (NB + NB*NPER/64) : NB;
  const int grid = cbase + NCONS;
  hipLaunchKernelGGL(k_zero, dim3(1),    dim3(64),    0, stream, dout);
  hipLaunchKernelGGL(k_fps,  dim3(grid), dim3(FPS_T), FPS_LDS, stream,
                     pos, dout, x, W1, hp, nbr, cnt, cbase);
  if (use_pre) {
    hipLaunchKernelGGL(k_conv2, dim3(MTOT), dim3(128), 0, stream,
                       hp, pos, W1, b1, W2, b2, nbr, cnt, dout);
  } else {
    hipLaunchKernelGGL(k_conv,  dim3(MTOT), dim3(128), 0, stream,
                       x, pos, W1, b1, W2, b2, nbr, cnt, dout);
  }
}

// Round 8
// 3118.205 us; speedup vs baseline: 1.0088x; 1.0088x over previous
//
#include <hip/hip_runtime.h>
#include <stdint.h>

#define NPER 8192
#define NB 4
#define MPER 4096
#define MTOT (NB*MPER)      // 16384
#define KNB 64
#define CIN 64
#define R2C 0.04f           // f32-nearest of python 0.2*0.2 (NOT 0.2f*0.2f!)

// d_out (floats): x_out [MTOT*128] | pos_out [MTOT*3] | batch_out [MTOT]
#define POSOUT_OFF (MTOT*128)
#define BATCH_OFF  (MTOT*128 + MTOT*3)

// ws layout (primary/use_pre path):
//   scratch SSTR*NB floats @0 (544KB; old nbr region, nbr unused here) |
//   cnt i32 [MTOT] @2MB (unused in primary) |
//   precomp hp f32[32768*64] @PRE_OFF (8MB)
// R18: scratch MOVED dout->ws. R17 crashed: fused k_rc2 wrote x_out
// (dout[m*128..)) over the scratch CS/SX tables (dout[0..139264)) while
// other blocks still scanned them -> garbage CS segment bounds -> unbounded
// SX[i] reads -> memory fault. In ws, conv output overlaps nothing.
// R19: byte-identical resubmit of R18 — R18's bench died with the
// "container failed twice" INFRA signature (same as R14, whose identical
// resubmit then passed). Kernel re-audited: no spins, no aliasing, uniform
// barriers, static launch topology.
// Fallback path keeps scratch in dout (separate dispatches, proven safe).
#define PRE_OFF 2162688ull
#define PRE_BYTES 8388608ull

// scratch, per cloud stride SSTR floats: SX[8192] @0 | SY @8192 | SZ @16384 |
// SO u16[8192] @24576f | CS u32[513] @28672f (sorted by lex cell) |
// PERM u16[8192] @29200f (brick-major pos -> lex slot, init-only)
#define SSTR 34816
#define PERM_F 29200

typedef float v2f __attribute__((ext_vector_type(2)));

// ---------------------------------------------------------------- K1: FPS
// R10/R12-proven exact lazy FPS. LOOP AND CONFIG FROZEN. History:
//   R5/R9/R11: reduce/tail edits regressed. R12 ownership: NULL.
//   R13 (8x16): +44% — passing-wave serial update is the critical path.
//   R14/R15: k_pre fused as burst blocks — banked −94us (burst also leaves
//     clocks boosted: fused FPS 2400 vs 2516 standalone).
//   R16 (streamed radius consumers): producer 2400->2805 (+17%) — SUSTAINED
//     background occupancy drops the serial loop's clock; burst work is
//     fine, sustained is not. RULE: nothing runs concurrently with the FPS
//     main loop beyond a short burst.
// 1024 thr, 8 pts/thread brick-sorted via perm, AABB prune w/ fresh lmax
// (provably-exact skip: 1.2e-4 margin >> 5e-7 f32 rounding), bitwise-numpy
// update ((dx*dx+dy*dy)+dz*dz, rn, no fma), key=(bd<<26)|brk (max d2,
// tie -> min orig = np.argmax first-max), DPP wave max + single-owner
// readlane, per-wave LDS atomicMax into 3-phase slot, ONE barrier/iter.
#define FPS_T 1024
#define PTS 8
#define NCELL 512

// dynamic-LDS layout (bytes)
#define OFF_XS 0
#define OFF_YS (OFF_XS + NPER*4)        // 32768
#define OFF_ZS (OFF_YS + NPER*4)        // 65536
#define OFF_OS (OFF_ZS + NPER*4)        // 98304  u16[8192]
#define OFF_WIN (OFF_OS + NPER*2)       // 114688 u16[4096]
#define OFF_HIST (OFF_WIN + MPER*2)     // 122880 u32[512]
#define OFF_SCAN (OFF_HIST + NCELL*4)   // 124928 u32[512]
#define OFF_SLOT (OFF_SCAN + NCELL*4)   // 126976 u64[3]
#define OFF_SID0 (OFF_SLOT + 24)        // 127000 u32
#define OFF_BSC  (OFF_SID0 + 8)         // 127008 u32[512] (brick scan)
#define FPS_LDS  (OFF_BSC + NCELL*4)    // 129056 B

template<int CTRL>
__device__ __forceinline__ unsigned dppmax(unsigned v) {
  unsigned t = (unsigned)__builtin_amdgcn_update_dpp(
      0, (int)v, CTRL, 0xf, 0xf, true);   // bound_ctrl: OOB lanes read 0
  return v > t ? v : t;
}
__device__ __forceinline__ unsigned wave_max_u32(unsigned v) {
  v = dppmax<0x111>(v);   // row_shr:1
  v = dppmax<0x112>(v);   // row_shr:2
  v = dppmax<0x114>(v);   // row_shr:4
  v = dppmax<0x118>(v);   // row_shr:8
  v = dppmax<0x142>(v);   // row_bcast15
  v = dppmax<0x143>(v);   // row_bcast31
  return (unsigned)__builtin_amdgcn_readlane((int)v, 63);
}

// brick-major cell index: brick = 4x4x2 cells (0.5 x 0.5 x 0.25), 16 bricks
// == 16 waves; bijection over [0,512).
__device__ __forceinline__ unsigned brick_key(unsigned c) {
  unsigned ix = c >> 6, iy = (c >> 3) & 7, iz = c & 7;
  unsigned bid = ((ix >> 2) << 3) | ((iy >> 2) << 2) | (iz >> 1);
  unsigned lid = ((ix & 3) << 3) | ((iy & 3) << 1) | (iz & 1);
  return (bid << 5) | lid;
}

__global__ __launch_bounds__(1024) void k_fps(const float* __restrict__ pos,
                                              float* __restrict__ dout,
                                              float* __restrict__ scr,
                                              const float* __restrict__ xin,
                                              const float* __restrict__ W1,
                                              float* __restrict__ hp)
{
#pragma clang fp contract(off)
  extern __shared__ char smem[];
  const int tid = threadIdx.x;

  // ---- fused k_pre blocks: hp = x @ W1[:64], bitwise == old k_pre.
  // Burst work on idle CUs; retires in ~40us (also leaves clocks boosted).
  if (blockIdx.x >= NB) {
    float* Ws = (float*)smem;                    // [64*64] ch-major
    float* Xs2 = (float*)(smem + 16384);         // [64][65]
    const int row0 = (blockIdx.x - NB) * 64;
    for (int e = tid; e < 64*64; e += FPS_T) Ws[e] = W1[e];
    for (int e = tid; e < 64*64; e += FPS_T) {
      int r = e >> 6, ch = e & 63;
      Xs2[r*65 + ch] = xin[(size_t)(row0 + r) * 64 + ch];
    }
    __syncthreads();                             // all 16 waves participate
    if (tid < 256) {
      const int rg = tid >> 4, cg = tid & 15;
      const int r0 = rg << 2, c0 = cg << 2;
      float acc[4][4];
#pragma unroll
      for (int r = 0; r < 4; ++r)
#pragma unroll
        for (int c = 0; c < 4; ++c) acc[r][c] = 0.0f;
      for (int k = 0; k < 64; ++k) {
        const float4 w = *(const float4*)&Ws[(k << 6) + c0];
        const float xr[4] = {Xs2[(r0+0)*65 + k], Xs2[(r0+1)*65 + k],
                             Xs2[(r0+2)*65 + k], Xs2[(r0+3)*65 + k]};
        const float wc[4] = {w.x, w.y, w.z, w.w};
#pragma unroll
        for (int r = 0; r < 4; ++r)
#pragma unroll
          for (int c = 0; c < 4; ++c)
            acc[r][c] = fmaf(xr[r], wc[c], acc[r][c]);
      }
#pragma unroll
      for (int r = 0; r < 4; ++r) {
        float4 o = {acc[r][0], acc[r][1], acc[r][2], acc[r][3]};
        *(float4*)&hp[(size_t)(row0 + r0 + r) * 64 + c0] = o;
      }
    }
    return;
  }

  float* Xs = (float*)(smem + OFF_XS);
  float* Ys = (float*)(smem + OFF_YS);
  float* Zs = (float*)(smem + OFF_ZS);
  unsigned short* Os = (unsigned short*)(smem + OFF_OS);
  unsigned short* winb = (unsigned short*)(smem + OFF_WIN);
  unsigned* hist = (unsigned*)(smem + OFF_HIST);
  unsigned* scanb = (unsigned*)(smem + OFF_SCAN);
  unsigned long long* slot3 = (unsigned long long*)(smem + OFF_SLOT);
  unsigned* sid0p = (unsigned*)(smem + OFF_SID0);
  unsigned* bsc = (unsigned*)(smem + OFF_BSC);

  const int b = blockIdx.x;
  const float* pb = pos + (size_t)b * NPER * 3;
  float* qo = dout + POSOUT_OFF + (size_t)b * MPER * 3;
  float* scrb = scr + (size_t)b * SSTR;
  float* gSX = scrb; float* gSY = scrb + 8192; float* gSZ = scrb + 16384;
  unsigned* gSO = (unsigned*)(scrb + 24576);       // packed u16 pairs
  unsigned* gCS = (unsigned*)(scrb + 28672);       // 513 entries
  unsigned short* gPM = (unsigned short*)(scrb + PERM_F);  // perm

  if (tid < NCELL) hist[tid] = 0u;
  if (tid == 0) { slot3[0] = 0ull; slot3[1] = 0ull; slot3[2] = 0ull; }
  __syncthreads();

  // ---- sort pass 1: count (lex cell) ----
  float sxv[PTS], syv[PTS], szv[PTS];
  unsigned cellv[PTS];
#pragma unroll
  for (int k = 0; k < PTS; ++k) {
    int i = k * FPS_T + tid;
    sxv[k] = pb[i*3+0]; syv[k] = pb[i*3+1]; szv[k] = pb[i*3+2];
    unsigned ix = min(7u, (unsigned)(int)(sxv[k] * 8.0f));
    unsigned iy = min(7u, (unsigned)(int)(syv[k] * 8.0f));
    unsigned iz = min(7u, (unsigned)(int)(szv[k] * 8.0f));
    cellv[k] = (ix << 6) | (iy << 3) | iz;
    atomicAdd(&hist[cellv[k]], 1u);
  }
  __syncthreads();
  // ---- scan -> exclusive starts; export CS to global ----
  if (tid < NCELL) scanb[tid] = hist[tid];
  __syncthreads();
  for (int s = 1; s < NCELL; s <<= 1) {
    unsigned v = 0u;
    if (tid >= s && tid < NCELL) v = scanb[tid - s];
    __syncthreads();
    if (tid >= s && tid < NCELL) scanb[tid] += v;
    __syncthreads();
  }
  if (tid < NCELL) {
    hist[tid] = scanb[tid] - hist[tid];   // exclusive start
    gCS[tid+1] = scanb[tid];              // start of cell tid+1
  }
  if (tid == 0) gCS[0] = 0u;
  __syncthreads();
  // ---- brick-order scan (wave-compact ownership) ----
  if (tid < NCELL) {
    unsigned c = (unsigned)tid;
    unsigned cntc = scanb[c] - hist[c];
    bsc[brick_key(c)] = cntc;             // counts in brick-major order
  }
  __syncthreads();
  for (int s = 1; s < NCELL; s <<= 1) {
    unsigned v = 0u;
    if (tid >= s && tid < NCELL) v = bsc[tid - s];
    __syncthreads();
    if (tid >= s && tid < NCELL) bsc[tid] += v;
    __syncthreads();
  }
  {
    unsigned bst = 0u;
    if (tid < NCELL) {
      unsigned c = (unsigned)tid;
      unsigned cntc = scanb[c] - hist[c];
      bst = bsc[brick_key(c)] - cntc;     // brick-order exclusive start
    }
    __syncthreads();
    if (tid < NCELL) bsc[tid] = bst;      // re-index by CELL: pass-2 counters
  }
  __syncthreads();
  // ---- sort pass 2: scatter into LDS (lex) + perm (brick-major) ----
#pragma unroll
  for (int k = 0; k < PTS; ++k) {
    unsigned dst = atomicAdd(&hist[cellv[k]], 1u);
    unsigned p   = atomicAdd(&bsc[cellv[k]], 1u);
    int orig = k * FPS_T + tid;
    Xs[dst] = sxv[k]; Ys[dst] = syv[k]; Zs[dst] = szv[k];
    Os[dst] = (unsigned short)orig;
    gPM[p] = (unsigned short)dst;         // brick pos p -> lex slot dst
    if (orig == 0) *sid0p = dst;
  }
  __syncthreads();
  // ---- dump sorted cloud to global scratch (for radius phase) ----
  for (int e = tid; e < NPER; e += FPS_T) {
    gSX[e] = Xs[e]; gSY[e] = Ys[e]; gSZ[e] = Zs[e];
  }
  for (int e = tid; e < NPER/2; e += FPS_T)
    gSO[e] = ((const unsigned*)Os)[e];
  // ---- own 8 brick-contiguous points (via perm) + AABB ----
  v2f Xp[4], Yp[4], Zp[4], Dp[4];
  unsigned RK[PTS];
  float bxlo = 3.402823466e+38f, bylo = bxlo, bzlo = bxlo;
  float bxhi = -bxlo, byhi = bxhi, bzhi = bxhi;
#pragma unroll
  for (int k = 0; k < PTS; ++k) {
    int s = (int)gPM[tid * PTS + k];
    float xx = Xs[s], yy = Ys[s], zz = Zs[s];
    Xp[k>>1][k&1] = xx; Yp[k>>1][k&1] = yy; Zp[k>>1][k&1] = zz;
    Dp[k>>1][k&1] = 3.402823466e+38f;
    unsigned orig = Os[s];
    RK[k] = ((unsigned)(NPER - 1 - orig) << 13) | (unsigned)s;
    bxlo = fminf(bxlo, xx); bxhi = fmaxf(bxhi, xx);
    bylo = fminf(bylo, yy); byhi = fmaxf(byhi, yy);
    bzlo = fminf(bzlo, zz); bzhi = fmaxf(bzhi, zz);
  }

  // ---- main loop (UNCHANGED — R10-proven; FROZEN) ----
  unsigned long long tkey = 0ull, wkey = 0ull;
  float lmax = 3.402823466e+38f;
  unsigned sidx = *sid0p;
  for (int m = 1; m < MPER; ++m) {
    const float cx = Xs[sidx], cy = Ys[sidx], cz = Zs[sidx];  // broadcasts
    if (tid == 0) winb[m-1] = (unsigned short)sidx;
    if (tid == 1) slot3[(m+1) % 3] = 0ull;   // phase-safe future reset
    float ax = fmaxf(fmaxf(__fsub_rn(bxlo, cx), __fsub_rn(cx, bxhi)), 0.0f);
    float ay = fmaxf(fmaxf(__fsub_rn(bylo, cy), __fsub_rn(cy, byhi)), 0.0f);
    float az = fmaxf(fmaxf(__fsub_rn(bzlo, cz), __fsub_rn(cz, bzhi)), 0.0f);
    float lb = ax*ax + ay*ay + az*az;
    bool upd = (lb * 0.99988f) < lmax;  // margin >> rounding: skip is exact
    if (__ballot(upd) != 0ull) {        // whole wave can skip
      if (upd) {
        v2f cx2 = {cx, cx}, cy2 = {cy, cy}, cz2 = {cz, cz};
        v2f dnp[4];
        float bd = -1.0f;
#pragma unroll
        for (int p = 0; p < 4; ++p) {
          v2f dx = Xp[p] - cx2;
          v2f dy = Yp[p] - cy2;
          v2f dz = Zp[p] - cz2;
          v2f s = (dx*dx + dy*dy) + dz*dz;   // rn, no fma (contract off)
          v2f dn;
          dn.x = fminf(Dp[p].x, s.x);
          dn.y = fminf(Dp[p].y, s.y);
          Dp[p] = dn; dnp[p] = dn;
          bd = fmaxf(bd, fmaxf(dn.x, dn.y));
        }
        unsigned brk = 0u;
#pragma unroll
        for (int p = 0; p < 4; ++p) {
          brk = (dnp[p].x == bd) ? max(brk, RK[2*p])   : brk;
          brk = (dnp[p].y == bd) ? max(brk, RK[2*p+1]) : brk;
        }
        tkey = ((unsigned long long)__float_as_uint(bd) << 26) | brk;
        lmax = bd;
      }
      unsigned hi = (unsigned)(tkey >> 26);
      unsigned M = wave_max_u32(hi);
      unsigned rk = (unsigned)tkey & 0x3FFFFFFu;
      unsigned long long msk = __ballot(hi == M);
      unsigned lo;
      if (__popcll(msk) == 1) {          // sole owner (the ~always case)
        int ln = (int)__builtin_ctzll(msk);
        lo = (unsigned)__builtin_amdgcn_readlane((int)rk, ln);
      } else {                           // exact d2 tie: max RK = min orig
        lo = wave_max_u32((hi == M) ? rk : 0u);
      }
      wkey = ((unsigned long long)M << 26) | lo;
    }
    if ((tid & 63) == 0) atomicMax(&slot3[m % 3], wkey);
    __syncthreads();
    sidx = (unsigned)(slot3[m % 3] & 0x1FFFull);
  }
  if (tid == 0) winb[MPER-1] = (unsigned short)sidx;
  __syncthreads();
  // reconstruct pos_out from LDS
  for (int e = tid; e < MPER; e += FPS_T) {
    unsigned s = winb[e];
    qo[e*3+0] = Xs[s]; qo[e*3+1] = Ys[s]; qo[e*3+2] = Zs[s];
  }
}

// ------------------------------------------------- K2: radius + top-K select
// (FALLBACK PATH ONLY when ws lacks precomp space; primary path uses k_rc2.)
#define SCAP 512
__global__ __launch_bounds__(256) void k_radius(const float* __restrict__ scr,
    float* __restrict__ dout, unsigned short* __restrict__ nbr,
    int* __restrict__ cnt)
{
  __shared__ unsigned candH[4][SCAP];
  __shared__ unsigned candL[4][SCAP];
  const int wid = threadIdx.x >> 6, lane = threadIdx.x & 63;
  const int m = blockIdx.x * 4 + wid;
  const int b = m >> 12;
  const float* scrb = scr + (size_t)b * SSTR;
  const float* SX = scrb;
  const float* SY = scrb + 8192;
  const float* SZ = scrb + 16384;
  const unsigned short* SO = (const unsigned short*)(scrb + 24576);
  const unsigned* CS = (const unsigned*)(scrb + 28672);
  const float* q = dout + POSOUT_OFF + (size_t)m * 3;
  const float qx = q[0], qy = q[1], qz = q[2];
  const int ixc = min(7, (int)(qx * 8.0f));
  const int iyc = min(7, (int)(qy * 8.0f));
  const int izc = min(7, (int)(qz * 8.0f));
  const int izlo = max(izc-2, 0), izhi = min(izc+2, 7);
  unsigned s0v = 0u, s1v = 0u;
  {
    int ix = ixc + lane / 5 - 2;
    int iy = iyc + lane % 5 - 2;
    if (lane < 25 && ix >= 0 && ix < 8 && iy >= 0 && iy < 8) {
      int cb = (ix << 6) | (iy << 3);
      s0v = CS[cb + izlo];
      s1v = CS[cb + izhi + 1];
    }
  }
  unsigned cw = 0;
  for (int seg = 0; seg < 25; ++seg) {
    unsigned s0 = (unsigned)__builtin_amdgcn_readlane((int)s0v, seg);
    unsigned s1 = (unsigned)__builtin_amdgcn_readlane((int)s1v, seg);
    for (unsigned i0 = s0; i0 < s1; i0 += 64) {
      unsigned i = i0 + (unsigned)lane;     // OOB lanes read harmless bytes
      float dx = __fsub_rn(qx, SX[i]);
      float dy = __fsub_rn(qy, SY[i]);
      float dz = __fsub_rn(qz, SZ[i]);
      float d2 = __fadd_rn(__fadd_rn(__fmul_rn(dx,dx), __fmul_rn(dy,dy)),
                           __fmul_rn(dz,dz));
      bool in = (i < s1) && (d2 <= R2C);
      unsigned long long mk = __ballot(in);
      unsigned pre = (unsigned)__popcll(mk & ((1ull << lane) - 1ull));
      if (in) {
        unsigned slot = cw + pre;
        if (slot < SCAP) {
          candH[wid][slot] = __float_as_uint(d2);
          candL[wid][slot] = (unsigned)SO[i];
        }
      }
      cw += (unsigned)__popcll(mk);
    }
  }
  if (cw > SCAP) cw = SCAP;
  for (int s = (int)cw + lane; s < SCAP; s += 64) {
    candH[wid][s] = 0xFFFFFFFFu; candL[wid][s] = 0xFFFFFFFFu;
  }
  __syncthreads();
  for (int k = 2; k <= SCAP; k <<= 1) {
    for (int j = k >> 1; j > 0; j >>= 1) {
#pragma unroll
      for (int s = 0; s < SCAP/128; ++s) {
        int t = lane + (s << 6);
        int e = ((t & ~(j-1)) << 1) | (t & (j-1));
        int p = e | j;
        unsigned aH = candH[wid][e], aL = candL[wid][e];
        unsigned cH = candH[wid][p], cL = candL[wid][p];
        bool agt = (aH > cH) || (aH == cH && aL > cL);
        bool asc = ((e & k) == 0);
        bool sw = asc ? agt : !agt && (aH != cH || aL != cL);
        if (sw) {
          candH[wid][e] = cH; candL[wid][e] = cL;
          candH[wid][p] = aH; candL[wid][p] = aL;
        }
      }
      __syncthreads();
    }
  }
  int kk = (int)cw; if (kk > KNB) kk = KNB;
  nbr[(size_t)m*KNB + lane] =
    (lane < kk) ? (unsigned short)(candL[wid][lane] & 0xFFFFu)
                : (unsigned short)0;
  if (lane == 0) {
    cnt[m] = kk;
    dout[BATCH_OFF + m] = (float)b;   // batch_out (buffer read as f32)
  }
}

// -------------------------- K_rc2: FUSED radius + conv2 (primary, R17/R18)
// One block (128 thr) per centroid. Phase 1: wave0 runs the EXACT proven
// candidate scan (bit-identical compaction); 128-thr bitonic covers the
// same pair set (t2 in [0,256) as t + s*128 vs lane + s*64 — identical
// swaps); nbr/cnt stay in LDS (no 2MB ws round-trip, no dispatch gap).
// Phase 2: proven k_conv2 code verbatim, nbr_s/cnt_s sourced from phase 1.
// cand arrays alias bufA (consumed before conv gather overwrites).
// R18: scratch is in ws (scr), NOT dout — conv's x_out writes no longer
// race with other blocks' scratch reads (the R17 fault).
__global__ __launch_bounds__(128) void k_rc2(
    const float* __restrict__ hp, const float* __restrict__ pos,
    const float* __restrict__ scr,
    const float* __restrict__ W1, const float* __restrict__ b1,
    const float* __restrict__ W2, const float* __restrict__ b2,
    float* __restrict__ dout)
{
  __shared__ __align__(16) float bufA[68*68];   // cand alias / h1T
  __shared__ __align__(16) float bufB[16*136];  // W2 chunk (stride 136)
  __shared__ float w1p[3*64];
  __shared__ unsigned short nbr_s[64];
  __shared__ float qv[3];
  __shared__ int cnt_s;
  unsigned* candH = (unsigned*)bufA;            // [SCAP]
  unsigned* candL = candH + SCAP;               // [SCAP]
  const int t = threadIdx.x;
  const int m = blockIdx.x;
  const int b = m >> 12;
  const int wid = t >> 6, lane = t & 63;
  const float* scrb = scr + (size_t)b * SSTR;
  const float* SX = scrb;
  const float* SY = scrb + 8192;
  const float* SZ = scrb + 16384;
  const unsigned short* SO = (const unsigned short*)(scrb + 24576);
  const unsigned* CS = (const unsigned*)(scrb + 28672);

  // phase 0: q position, W1 tail, batch_out
  if (t >= 64 && t < 67) qv[t-64] = dout[POSOUT_OFF + (size_t)m*3 + (t-64)];
  if (t == 67) dout[BATCH_OFF + m] = (float)b;
  for (int e = t; e < 192; e += 128) w1p[e] = W1[64*64 + e];
  __syncthreads();
  const float qx = qv[0], qy = qv[1], qz = qv[2];

  // phase 1: candidate scan — wave0 only, EXACT k_radius logic
  if (wid == 0) {
    const int ixc = min(7, (int)(qx * 8.0f));
    const int iyc = min(7, (int)(qy * 8.0f));
    const int izc = min(7, (int)(qz * 8.0f));
    const int izlo = max(izc-2, 0), izhi = min(izc+2, 7);
    unsigned s0v = 0u, s1v = 0u;
    {
      int ix = ixc + lane / 5 - 2;
      int iy = iyc + lane % 5 - 2;
      if (lane < 25 && ix >= 0 && ix < 8 && iy >= 0 && iy < 8) {
        int cb = (ix << 6) | (iy << 3);
        s0v = CS[cb + izlo];
        s1v = CS[cb + izhi + 1];
      }
    }
    unsigned cw = 0;
    for (int seg = 0; seg < 25; ++seg) {
      unsigned s0 = (unsigned)__builtin_amdgcn_readlane((int)s0v, seg);
      unsigned s1 = (unsigned)__builtin_amdgcn_readlane((int)s1v, seg);
      for (unsigned i0 = s0; i0 < s1; i0 += 64) {
        unsigned i = i0 + (unsigned)lane;   // OOB lanes read harmless bytes
        float dx = __fsub_rn(qx, SX[i]);
        float dy = __fsub_rn(qy, SY[i]);
        float dz = __fsub_rn(qz, SZ[i]);
        float d2 = __fadd_rn(__fadd_rn(__fmul_rn(dx,dx), __fmul_rn(dy,dy)),
                             __fmul_rn(dz,dz));
        bool in = (i < s1) && (d2 <= R2C);
        unsigned long long mk = __ballot(in);
        unsigned pre = (unsigned)__popcll(mk & ((1ull << lane) - 1ull));
        if (in) {
          unsigned slot = cw + pre;
          if (slot < SCAP) {
            candH[slot] = __float_as_uint(d2);
            candL[slot] = (unsigned)SO[i];
          }
        }
        cw += (unsigned)__popcll(mk);
      }
    }
    if (cw > SCAP) cw = SCAP;
    for (int s = (int)cw + lane; s < SCAP; s += 64) {
      candH[s] = 0xFFFFFFFFu; candL[s] = 0xFFFFFFFFu;
    }
    if (lane == 0) {
      int kk = (int)cw; if (kk > KNB) kk = KNB;
      cnt_s = kk;
    }
  }
  __syncthreads();
  // 128-thread bitonic: same pair set per (k,j) pass as the proven 64-lane
  // version (t2 in [0,256)), so identical swap sequence.
  for (int k = 2; k <= SCAP; k <<= 1) {
    for (int j = k >> 1; j > 0; j >>= 1) {
#pragma unroll
      for (int s = 0; s < SCAP/256; ++s) {
        int t2 = t + (s << 7);
        int e = ((t2 & ~(j-1)) << 1) | (t2 & (j-1));
        int p = e | j;
        unsigned aH = candH[e], aL = candL[e];
        unsigned cH = candH[p], cL = candL[p];
        bool agt = (aH > cH) || (aH == cH && aL > cL);
        bool asc = ((e & k) == 0);
        bool sw = asc ? agt : !agt && (aH != cH || aL != cL);
        if (sw) {
          candH[e] = cH; candL[e] = cL;
          candH[p] = aH; candL[p] = aL;
        }
      }
      __syncthreads();
    }
  }
  if (t < 64)
    nbr_s[t] = (t < cnt_s) ? (unsigned short)(candL[t] & 0xFFFFu)
                           : (unsigned short)0;
  __syncthreads();   // cand consumed; bufA free for conv gather

  // phase 2: conv (proven k_conv2 code verbatim; nbr_s/cnt_s from LDS)
  {                                   // gather hp rows -> h1T rows 0..63
    const int h = t & 63, jj = t >> 6;
    const size_t hb = (size_t)b * NPER * 64;
    for (int j0 = 0; j0 < 64; j0 += 2) {
      int j = j0 + jj;
      int r = nbr_s[j];
      bufA[h*68 + j] = hp[hb + (size_t)r*64 + h];
    }
  }
  {                                   // rel -> rows 64..66
    const size_t pbb = (size_t)b * NPER * 3;
    for (int e = t; e < 192; e += 128) {
      int j = e & 63, d = e >> 6;
      int r = nbr_s[j];
      bufA[(64+d)*68 + j] = pos[pbb + (size_t)r*3 + d] - qv[d];
    }
  }
  __syncthreads();
  // fuse: h1T[h][j] = relu(h1T + rel@w1p + b1)  (fmaf order 64,65,66, +b1)
  for (int e = t; e < 64*64; e += 128) {
    int h = e >> 6, j = e & 63;
    float v = bufA[h*68 + j];
    v = fmaf(bufA[64*68 + j], w1p[h],       v);
    v = fmaf(bufA[65*68 + j], w1p[64 + h],  v);
    v = fmaf(bufA[66*68 + j], w1p[128 + h], v);
    bufA[h*68 + j] = fmaxf(v + b1[h], 0.0f);
  }
  const int jg = t & 7, hg = t >> 3;
  const int j0 = jg << 3;
  const int c0 = hg << 3;             // stage2: 8j x 8c packed pairs
  v2f acc2p[8][4];                    // [c][jpair]
#pragma unroll
  for (int c = 0; c < 8; ++c)
#pragma unroll
    for (int jp = 0; jp < 4; ++jp) acc2p[c][jp] = (v2f){0.0f, 0.0f};
  for (int hc = 0; hc < 64; hc += 16) {
    __syncthreads();                  // h1T ready / prior chunk consumed
    for (int e = t; e < 16*128; e += 128) {
      int hh = e >> 7, c = e & 127;
      bufB[hh*136 + c] = W2[(size_t)(hc+hh)*128 + c];
    }
    __syncthreads();
#pragma unroll
    for (int h = 0; h < 16; ++h) {
      const float4 ja = *(const float4*)&bufA[(hc+h)*68 + j0];
      const float4 jb = *(const float4*)&bufA[(hc+h)*68 + j0 + 4];
      const float4 wa = *(const float4*)&bufB[h*136 + c0];
      const float4 wb = *(const float4*)&bufB[h*136 + c0 + 4];
      const v2f hj[4] = {{ja.x, ja.y}, {ja.z, ja.w}, {jb.x, jb.y}, {jb.z, jb.w}};
      const float wv[8] = {wa.x, wa.y, wa.z, wa.w, wb.x, wb.y, wb.z, wb.w};
#pragma unroll
      for (int c = 0; c < 8; ++c) {
        const v2f w2 = {wv[c], wv[c]};
#pragma unroll
        for (int jp = 0; jp < 4; ++jp)
          acc2p[c][jp] += w2 * hj[jp];          // v_pk_fma_f32
      }
    }
  }
  const int cntv = cnt_s;
  const float4 b2a = *(const float4*)&b2[c0];
  const float4 b2b = *(const float4*)&b2[c0 + 4];
  const float bv2[8] = {b2a.x, b2a.y, b2a.z, b2a.w, b2b.x, b2b.y, b2b.z, b2b.w};
  float best[8];
#pragma unroll
  for (int c = 0; c < 8; ++c) {
    float v = -3.402823466e+38f;
#pragma unroll
    for (int jp = 0; jp < 4; ++jp) {
      float h0v = fmaxf(acc2p[c][jp].x + bv2[c], 0.0f);
      float h1v = fmaxf(acc2p[c][jp].y + bv2[c], 0.0f);
      v = (j0 + 2*jp     < cntv) ? fmaxf(v, h0v) : v;
      v = (j0 + 2*jp + 1 < cntv) ? fmaxf(v, h1v) : v;
    }
    best[c] = v;
  }
#pragma unroll
  for (int off = 1; off < 8; off <<= 1)
#pragma unroll
    for (int c = 0; c < 8; ++c)
      best[c] = fmaxf(best[c], __shfl_xor(best[c], off));
  if (jg == 0) {
    float4 o0 = {best[0], best[1], best[2], best[3]};
    float4 o1 = {best[4], best[5], best[6], best[7]};
    *(float4*)&dout[(size_t)m*128 + c0] = o0;
    *(float4*)&dout[(size_t)m*128 + c0 + 4] = o1;
  }
}

// --------------------------------------------- K3b: legacy conv (fallback)
__global__ __launch_bounds__(128) void k_conv(
    const float* __restrict__ x, const float* __restrict__ pos,
    const float* __restrict__ W1, const float* __restrict__ b1,
    const float* __restrict__ W2, const float* __restrict__ b2,
    const unsigned short* __restrict__ nbr, const int* __restrict__ cntp,
    float* __restrict__ dout)
{
  __shared__ __align__(16) float bufA[68*68];
  __shared__ __align__(16) float bufB[68*68];
  __shared__ unsigned short nbr_s[64];
  __shared__ float qv[3];
  __shared__ int cnt_s;
  const int t = threadIdx.x;
  const int m = blockIdx.x;
  const int b = m >> 12;
  if (t < 64) nbr_s[t] = nbr[(size_t)m*KNB + t];
  else if (t == 64) cnt_s = cntp[m];
  else if (t >= 65 && t < 68) qv[t-65] = dout[POSOUT_OFF + (size_t)m*3 + (t-65)];
  for (int e = t; e < 67*64; e += 128) {
    int ch = e >> 6, h = e & 63;
    bufB[ch*68 + h] = W1[e];
  }
  __syncthreads();
  {
    const int ch = t & 63, jj = t >> 6;
    const size_t xb = (size_t)b * NPER * CIN;
    for (int j0 = 0; j0 < 64; j0 += 2) {
      int j = j0 + jj;
      int r = nbr_s[j];
      bufA[ch*68 + j] = x[xb + (size_t)r*CIN + ch];
    }
  }
  {
    const size_t pbb = (size_t)b * NPER * 3;
    for (int e = t; e < 192; e += 128) {
      int j = e & 63, d = e >> 6;
      int r = nbr_s[j];
      bufA[(64+d)*68 + j] = pos[pbb + (size_t)r*3 + d] - qv[d];
    }
  }
  __syncthreads();
  const int jg = t & 7, hg = t >> 3;
  const int j0 = jg << 3;
  const int h0 = hg << 2;
  v2f accp[4][4];
#pragma unroll
  for (int hh = 0; hh < 4; ++hh)
#pragma unroll
    for (int jp = 0; jp < 4; ++jp) accp[hh][jp] = (v2f){0.0f, 0.0f};
  for (int ch = 0; ch < 67; ++ch) {
    const float4 fa = *(const float4*)&bufA[ch*68 + j0];
    const float4 fb = *(const float4*)&bufA[ch*68 + j0 + 4];
    const float4 w  = *(const float4*)&bufB[ch*68 + h0];
    const v2f fj[4] = {{fa.x, fa.y}, {fa.z, fa.w}, {fb.x, fb.y}, {fb.z, fb.w}};
    const float ws4[4] = {w.x, w.y, w.z, w.w};
#pragma unroll
    for (int hh = 0; hh < 4; ++hh) {
      const v2f wv2 = {ws4[hh], ws4[hh]};
#pragma unroll
      for (int jp = 0; jp < 4; ++jp)
        accp[hh][jp] += wv2 * fj[jp];
    }
  }
  __syncthreads();
  {
    const float4 bb = *(const float4*)&b1[h0];
    const float bv[4] = {bb.x, bb.y, bb.z, bb.w};
#pragma unroll
    for (int hh = 0; hh < 4; ++hh) {
      float4 o0, o1;
      o0.x = fmaxf(accp[hh][0].x + bv[hh], 0.0f);
      o0.y = fmaxf(accp[hh][0].y + bv[hh], 0.0f);
      o0.z = fmaxf(accp[hh][1].x + bv[hh], 0.0f);
      o0.w = fmaxf(accp[hh][1].y + bv[hh], 0.0f);
      o1.x = fmaxf(accp[hh][2].x + bv[hh], 0.0f);
      o1.y = fmaxf(accp[hh][2].y + bv[hh], 0.0f);
      o1.z = fmaxf(accp[hh][3].x + bv[hh], 0.0f);
      o1.w = fmaxf(accp[hh][3].y + bv[hh], 0.0f);
      *(float4*)&bufA[(h0+hh)*68 + j0] = o0;
      *(float4*)&bufA[(h0+hh)*68 + j0 + 4] = o1;
    }
  }
  const int c0 = hg << 3;
  v2f acc2p[8][4];
#pragma unroll
  for (int c = 0; c < 8; ++c)
#pragma unroll
    for (int jp = 0; jp < 4; ++jp) acc2p[c][jp] = (v2f){0.0f, 0.0f};
  for (int hc = 0; hc < 64; hc += 16) {
    __syncthreads();
    for (int e = t; e < 16*128; e += 128) {
      int hh = e >> 7, c = e & 127;
      bufB[hh*136 + c] = W2[(size_t)(hc+hh)*128 + c];
    }
    __syncthreads();
#pragma unroll
    for (int h = 0; h < 16; ++h) {
      const float4 ja = *(const float4*)&bufA[(hc+h)*68 + j0];
      const float4 jb = *(const float4*)&bufA[(hc+h)*68 + j0 + 4];
      const float4 wa = *(const float4*)&bufB[h*136 + c0];
      const float4 wb = *(const float4*)&bufB[h*136 + c0 + 4];
      const v2f hj[4] = {{ja.x, ja.y}, {ja.z, ja.w}, {jb.x, jb.y}, {jb.z, jb.w}};
      const float wv[8] = {wa.x, wa.y, wa.z, wa.w, wb.x, wb.y, wb.z, wb.w};
#pragma unroll
      for (int c = 0; c < 8; ++c) {
        const v2f w2 = {wv[c], wv[c]};
#pragma unroll
        for (int jp = 0; jp < 4; ++jp)
          acc2p[c][jp] += w2 * hj[jp];
      }
    }
  }
  const int cntv = cnt_s;
  const float4 b2a = *(const float4*)&b2[c0];
  const float4 b2b = *(const float4*)&b2[c0 + 4];
  const float bv2[8] = {b2a.x, b2a.y, b2a.z, b2a.w, b2b.x, b2b.y, b2b.z, b2b.w};
  float best[8];
#pragma unroll
  for (int c = 0; c < 8; ++c) {
    float v = -3.402823466e+38f;
#pragma unroll
    for (int jp = 0; jp < 4; ++jp) {
      float h0v = fmaxf(acc2p[c][jp].x + bv2[c], 0.0f);
      float h1v = fmaxf(acc2p[c][jp].y + bv2[c], 0.0f);
      v = (j0 + 2*jp     < cntv) ? fmaxf(v, h0v) : v;
      v = (j0 + 2*jp + 1 < cntv) ? fmaxf(v, h1v) : v;
    }
    best[c] = v;
  }
#pragma unroll
  for (int off = 1; off < 8; off <<= 1)
#pragma unroll
    for (int c = 0; c < 8; ++c)
      best[c] = fmaxf(best[c], __shfl_xor(best[c], off));
  if (jg == 0) {
    float4 o0 = {best[0], best[1], best[2], best[3]};
    float4 o1 = {best[4], best[5], best[6], best[7]};
    *(float4*)&dout[(size_t)m*128 + c0] = o0;
    *(float4*)&dout[(size_t)m*128 + c0 + 4] = o1;
  }
}

extern "C" void kernel_launch(void* const* d_in, const int* in_sizes, int n_in,
                              void* d_out, int out_size, void* d_ws, size_t ws_size,
                              hipStream_t stream) {
  const float* x   = (const float*)d_in[0];
  const float* pos = (const float*)d_in[1];
  // d_in[2] = batch (layout known statically, unused)
  const float* W1  = (const float*)d_in[3];
  const float* b1  = (const float*)d_in[4];
  const float* W2  = (const float*)d_in[5];
  const float* b2  = (const float*)d_in[6];
  float* dout = (float*)d_out;
  unsigned short* nbr = (unsigned short*)d_ws;
  int* cnt = (int*)((char*)d_ws + (size_t)MTOT*KNB*2);
  float* hp = (float*)((char*)d_ws + PRE_OFF);
  const bool use_pre = (ws_size >= PRE_OFF + PRE_BYTES);  // constant per run

  // R18: scratch base — ws (primary; avoids the R17 x_out/scratch race) or
  // dout (fallback; separate dispatches make it safe there).
  float* scr = use_pre ? (float*)d_ws : dout;

  const int grid = use_pre ? (NB + NB*NPER/64) : NB;
  hipLaunchKernelGGL(k_fps, dim3(grid), dim3(FPS_T), FPS_LDS, stream,
                     pos, dout, scr, x, W1, hp);
  if (use_pre) {
    hipLaunchKernelGGL(k_rc2, dim3(MTOT), dim3(128), 0, stream,
                       hp, pos, scr, W1, b1, W2, b2, dout);
  } else {
    hipLaunchKernelGGL(k_radius, dim3(MTOT/4), dim3(256), 0, stream,
                       scr, dout, nbr, cnt);
    hipLaunchKernelGGL(k_conv,   dim3(MTOT),   dim3(128), 0, stream,
                       x, pos, W1, b1, W2, b2, nbr, cnt, dout);
  }
}

// Round 9
// 2939.668 us; speedup vs baseline: 1.0701x; 1.0607x over previous
//
#include <hip/hip_runtime.h>
#include <stdint.h>

#define NPER 8192
#define NB 4
#define MPER 4096
#define MTOT (NB*MPER)      // 16384
#define KNB 64
#define CIN 64
#define R2C 0.04f           // f32-nearest of python 0.2*0.2 (NOT 0.2f*0.2f!)

// d_out (floats): x_out [MTOT*128] | pos_out [MTOT*3] | batch_out [MTOT]
#define POSOUT_OFF (MTOT*128)
#define BATCH_OFF  (MTOT*128 + MTOT*3)

// ws: nbr u16 [MTOT*64] @0 (2MB) | cnt i32 [MTOT] @2MB (64KB) |
//     precomp f32[32768*64] @PRE_OFF (8MB, optional: ws_size-gated)
#define PRE_OFF 2162688ull
#define PRE_BYTES 8388608ull

// fps->radius scratch in x_out region of d_out (free until k_conv2; SAFE
// here because k_radius fully retires before k_conv2 writes x_out):
// per cloud stride SSTR floats: SX[8192] @0 | SY @8192 | SZ @16384 |
// SO u16[8192] @24576f | CS u32[513] @28672f (sorted by lex cell) |
// PERM u16[8192] @29200f (brick-major pos -> lex slot, init-only)
#define SSTR 34816
#define PERM_F 29200

typedef float v2f __attribute__((ext_vector_type(2)));

// ---------------------------------------------------------------- K1: FPS
// R20 = REVERT TO R15 (banked best, 2917us). Session ledger:
//   R5/R9/R11: FPS reduce/tail edits regressed. R12 ownership: NULL.
//   R13 (8x16): +44% — passing-wave serial update is the critical path;
//     16 waves x 8 pts is the empirical optimum (~2400-2500us, noise ±4%).
//   R14/R15: k_pre fused as burst blocks — WIN, −94us (burst also leaves
//     clocks boosted: fused FPS 2400 vs 2516 standalone).
//   R16 (streamed radius consumers): +17% on FPS — SUSTAINED background
//     occupancy drops the serial loop's clock. RULE: nothing runs
//     concurrently with the FPS main loop beyond a short burst.
//   R17/R19 (fused radius+conv k_rc2): R17 faulted (x_out/scratch alias);
//     R19 correct but tail 623 > split 517 — wave1 idles during the
//     1-wave scan and scan->sort->conv serialize per block, negating the
//     saved dispatch gap. Split pipeline wins; fusion abandoned.
// 1024 thr, 8 pts/thread brick-sorted via perm, AABB prune w/ fresh lmax
// (provably-exact skip: 1.2e-4 margin >> 5e-7 f32 rounding), bitwise-numpy
// update ((dx*dx+dy*dy)+dz*dz, rn, no fma), key=(bd<<26)|brk (max d2,
// tie -> min orig = np.argmax first-max), DPP wave max + single-owner
// readlane, per-wave LDS atomicMax into 3-phase slot, ONE barrier/iter.
#define FPS_T 1024
#define PTS 8
#define NCELL 512

// dynamic-LDS layout (bytes)
#define OFF_XS 0
#define OFF_YS (OFF_XS + NPER*4)        // 32768
#define OFF_ZS (OFF_YS + NPER*4)        // 65536
#define OFF_OS (OFF_ZS + NPER*4)        // 98304  u16[8192]
#define OFF_WIN (OFF_OS + NPER*2)       // 114688 u16[4096]
#define OFF_HIST (OFF_WIN + MPER*2)     // 122880 u32[512]
#define OFF_SCAN (OFF_HIST + NCELL*4)   // 124928 u32[512]
#define OFF_SLOT (OFF_SCAN + NCELL*4)   // 126976 u64[3]
#define OFF_SID0 (OFF_SLOT + 24)        // 127000 u32
#define OFF_BSC  (OFF_SID0 + 8)         // 127008 u32[512] (brick scan)
#define FPS_LDS  (OFF_BSC + NCELL*4)    // 129056 B

template<int CTRL>
__device__ __forceinline__ unsigned dppmax(unsigned v) {
  unsigned t = (unsigned)__builtin_amdgcn_update_dpp(
      0, (int)v, CTRL, 0xf, 0xf, true);   // bound_ctrl: OOB lanes read 0
  return v > t ? v : t;
}
__device__ __forceinline__ unsigned wave_max_u32(unsigned v) {
  v = dppmax<0x111>(v);   // row_shr:1
  v = dppmax<0x112>(v);   // row_shr:2
  v = dppmax<0x114>(v);   // row_shr:4
  v = dppmax<0x118>(v);   // row_shr:8
  v = dppmax<0x142>(v);   // row_bcast15
  v = dppmax<0x143>(v);   // row_bcast31
  return (unsigned)__builtin_amdgcn_readlane((int)v, 63);
}

// brick-major cell index: brick = 4x4x2 cells (0.5 x 0.5 x 0.25), 16 bricks
// == 16 waves; bijection over [0,512).
__device__ __forceinline__ unsigned brick_key(unsigned c) {
  unsigned ix = c >> 6, iy = (c >> 3) & 7, iz = c & 7;
  unsigned bid = ((ix >> 2) << 3) | ((iy >> 2) << 2) | (iz >> 1);
  unsigned lid = ((ix & 3) << 3) | ((iy & 3) << 1) | (iz & 1);
  return (bid << 5) | lid;
}

__global__ __launch_bounds__(1024) void k_fps(const float* __restrict__ pos,
                                              float* __restrict__ dout,
                                              const float* __restrict__ xin,
                                              const float* __restrict__ W1,
                                              float* __restrict__ hp)
{
#pragma clang fp contract(off)
  extern __shared__ char smem[];
  const int tid = threadIdx.x;

  // ---- fused k_pre blocks: hp = x @ W1[:64], bitwise == old k_pre.
  // Burst work on idle CUs; retires in ~40us (also leaves clocks boosted).
  if (blockIdx.x >= NB) {
    float* Ws = (float*)smem;                    // [64*64] ch-major
    float* Xs2 = (float*)(smem + 16384);         // [64][65]
    const int row0 = (blockIdx.x - NB) * 64;
    for (int e = tid; e < 64*64; e += FPS_T) Ws[e] = W1[e];
    for (int e = tid; e < 64*64; e += FPS_T) {
      int r = e >> 6, ch = e & 63;
      Xs2[r*65 + ch] = xin[(size_t)(row0 + r) * 64 + ch];
    }
    __syncthreads();                             // all 16 waves participate
    if (tid < 256) {
      const int rg = tid >> 4, cg = tid & 15;
      const int r0 = rg << 2, c0 = cg << 2;
      float acc[4][4];
#pragma unroll
      for (int r = 0; r < 4; ++r)
#pragma unroll
        for (int c = 0; c < 4; ++c) acc[r][c] = 0.0f;
      for (int k = 0; k < 64; ++k) {
        const float4 w = *(const float4*)&Ws[(k << 6) + c0];
        const float xr[4] = {Xs2[(r0+0)*65 + k], Xs2[(r0+1)*65 + k],
                             Xs2[(r0+2)*65 + k], Xs2[(r0+3)*65 + k]};
        const float wc[4] = {w.x, w.y, w.z, w.w};
#pragma unroll
        for (int r = 0; r < 4; ++r)
#pragma unroll
          for (int c = 0; c < 4; ++c)
            acc[r][c] = fmaf(xr[r], wc[c], acc[r][c]);
      }
#pragma unroll
      for (int r = 0; r < 4; ++r) {
        float4 o = {acc[r][0], acc[r][1], acc[r][2], acc[r][3]};
        *(float4*)&hp[(size_t)(row0 + r0 + r) * 64 + c0] = o;
      }
    }
    return;
  }

  float* Xs = (float*)(smem + OFF_XS);
  float* Ys = (float*)(smem + OFF_YS);
  float* Zs = (float*)(smem + OFF_ZS);
  unsigned short* Os = (unsigned short*)(smem + OFF_OS);
  unsigned short* winb = (unsigned short*)(smem + OFF_WIN);
  unsigned* hist = (unsigned*)(smem + OFF_HIST);
  unsigned* scanb = (unsigned*)(smem + OFF_SCAN);
  unsigned long long* slot3 = (unsigned long long*)(smem + OFF_SLOT);
  unsigned* sid0p = (unsigned*)(smem + OFF_SID0);
  unsigned* bsc = (unsigned*)(smem + OFF_BSC);

  const int b = blockIdx.x;
  const float* pb = pos + (size_t)b * NPER * 3;
  float* qo = dout + POSOUT_OFF + (size_t)b * MPER * 3;
  float* scrb = dout + (size_t)b * SSTR;
  float* gSX = scrb; float* gSY = scrb + 8192; float* gSZ = scrb + 16384;
  unsigned* gSO = (unsigned*)(scrb + 24576);       // packed u16 pairs
  unsigned* gCS = (unsigned*)(scrb + 28672);       // 513 entries
  unsigned short* gPM = (unsigned short*)(scrb + PERM_F);  // perm

  if (tid < NCELL) hist[tid] = 0u;
  if (tid == 0) { slot3[0] = 0ull; slot3[1] = 0ull; slot3[2] = 0ull; }
  __syncthreads();

  // ---- sort pass 1: count (lex cell) ----
  float sxv[PTS], syv[PTS], szv[PTS];
  unsigned cellv[PTS];
#pragma unroll
  for (int k = 0; k < PTS; ++k) {
    int i = k * FPS_T + tid;
    sxv[k] = pb[i*3+0]; syv[k] = pb[i*3+1]; szv[k] = pb[i*3+2];
    unsigned ix = min(7u, (unsigned)(int)(sxv[k] * 8.0f));
    unsigned iy = min(7u, (unsigned)(int)(syv[k] * 8.0f));
    unsigned iz = min(7u, (unsigned)(int)(szv[k] * 8.0f));
    cellv[k] = (ix << 6) | (iy << 3) | iz;
    atomicAdd(&hist[cellv[k]], 1u);
  }
  __syncthreads();
  // ---- scan -> exclusive starts; export CS to global ----
  if (tid < NCELL) scanb[tid] = hist[tid];
  __syncthreads();
  for (int s = 1; s < NCELL; s <<= 1) {
    unsigned v = 0u;
    if (tid >= s && tid < NCELL) v = scanb[tid - s];
    __syncthreads();
    if (tid >= s && tid < NCELL) scanb[tid] += v;
    __syncthreads();
  }
  if (tid < NCELL) {
    hist[tid] = scanb[tid] - hist[tid];   // exclusive start
    gCS[tid+1] = scanb[tid];              // start of cell tid+1
  }
  if (tid == 0) gCS[0] = 0u;
  __syncthreads();
  // ---- brick-order scan (wave-compact ownership) ----
  if (tid < NCELL) {
    unsigned c = (unsigned)tid;
    unsigned cntc = scanb[c] - hist[c];
    bsc[brick_key(c)] = cntc;             // counts in brick-major order
  }
  __syncthreads();
  for (int s = 1; s < NCELL; s <<= 1) {
    unsigned v = 0u;
    if (tid >= s && tid < NCELL) v = bsc[tid - s];
    __syncthreads();
    if (tid >= s && tid < NCELL) bsc[tid] += v;
    __syncthreads();
  }
  {
    unsigned bst = 0u;
    if (tid < NCELL) {
      unsigned c = (unsigned)tid;
      unsigned cntc = scanb[c] - hist[c];
      bst = bsc[brick_key(c)] - cntc;     // brick-order exclusive start
    }
    __syncthreads();
    if (tid < NCELL) bsc[tid] = bst;      // re-index by CELL: pass-2 counters
  }
  __syncthreads();
  // ---- sort pass 2: scatter into LDS (lex) + perm (brick-major) ----
#pragma unroll
  for (int k = 0; k < PTS; ++k) {
    unsigned dst = atomicAdd(&hist[cellv[k]], 1u);
    unsigned p   = atomicAdd(&bsc[cellv[k]], 1u);
    int orig = k * FPS_T + tid;
    Xs[dst] = sxv[k]; Ys[dst] = syv[k]; Zs[dst] = szv[k];
    Os[dst] = (unsigned short)orig;
    gPM[p] = (unsigned short)dst;         // brick pos p -> lex slot dst
    if (orig == 0) *sid0p = dst;
  }
  __syncthreads();
  // ---- dump sorted cloud to global scratch (for k_radius) ----
  for (int e = tid; e < NPER; e += FPS_T) {
    gSX[e] = Xs[e]; gSY[e] = Ys[e]; gSZ[e] = Zs[e];
  }
  for (int e = tid; e < NPER/2; e += FPS_T)
    gSO[e] = ((const unsigned*)Os)[e];
  // ---- own 8 brick-contiguous points (via perm) + AABB ----
  v2f Xp[4], Yp[4], Zp[4], Dp[4];
  unsigned RK[PTS];
  float bxlo = 3.402823466e+38f, bylo = bxlo, bzlo = bxlo;
  float bxhi = -bxlo, byhi = bxhi, bzhi = bxhi;
#pragma unroll
  for (int k = 0; k < PTS; ++k) {
    int s = (int)gPM[tid * PTS + k];
    float xx = Xs[s], yy = Ys[s], zz = Zs[s];
    Xp[k>>1][k&1] = xx; Yp[k>>1][k&1] = yy; Zp[k>>1][k&1] = zz;
    Dp[k>>1][k&1] = 3.402823466e+38f;
    unsigned orig = Os[s];
    RK[k] = ((unsigned)(NPER - 1 - orig) << 13) | (unsigned)s;
    bxlo = fminf(bxlo, xx); bxhi = fmaxf(bxhi, xx);
    bylo = fminf(bylo, yy); byhi = fmaxf(byhi, yy);
    bzlo = fminf(bzlo, zz); bzhi = fmaxf(bzhi, zz);
  }

  // ---- main loop (UNCHANGED — R10-proven; FROZEN) ----
  unsigned long long tkey = 0ull, wkey = 0ull;
  float lmax = 3.402823466e+38f;
  unsigned sidx = *sid0p;
  for (int m = 1; m < MPER; ++m) {
    const float cx = Xs[sidx], cy = Ys[sidx], cz = Zs[sidx];  // broadcasts
    if (tid == 0) winb[m-1] = (unsigned short)sidx;
    if (tid == 1) slot3[(m+1) % 3] = 0ull;   // phase-safe future reset
    float ax = fmaxf(fmaxf(__fsub_rn(bxlo, cx), __fsub_rn(cx, bxhi)), 0.0f);
    float ay = fmaxf(fmaxf(__fsub_rn(bylo, cy), __fsub_rn(cy, byhi)), 0.0f);
    float az = fmaxf(fmaxf(__fsub_rn(bzlo, cz), __fsub_rn(cz, bzhi)), 0.0f);
    float lb = ax*ax + ay*ay + az*az;
    bool upd = (lb * 0.99988f) < lmax;  // margin >> rounding: skip is exact
    if (__ballot(upd) != 0ull) {        // whole wave can skip
      if (upd) {
        v2f cx2 = {cx, cx}, cy2 = {cy, cy}, cz2 = {cz, cz};
        v2f dnp[4];
        float bd = -1.0f;
#pragma unroll
        for (int p = 0; p < 4; ++p) {
          v2f dx = Xp[p] - cx2;
          v2f dy = Yp[p] - cy2;
          v2f dz = Zp[p] - cz2;
          v2f s = (dx*dx + dy*dy) + dz*dz;   // rn, no fma (contract off)
          v2f dn;
          dn.x = fminf(Dp[p].x, s.x);
          dn.y = fminf(Dp[p].y, s.y);
          Dp[p] = dn; dnp[p] = dn;
          bd = fmaxf(bd, fmaxf(dn.x, dn.y));
        }
        unsigned brk = 0u;
#pragma unroll
        for (int p = 0; p < 4; ++p) {
          brk = (dnp[p].x == bd) ? max(brk, RK[2*p])   : brk;
          brk = (dnp[p].y == bd) ? max(brk, RK[2*p+1]) : brk;
        }
        tkey = ((unsigned long long)__float_as_uint(bd) << 26) | brk;
        lmax = bd;
      }
      unsigned hi = (unsigned)(tkey >> 26);
      unsigned M = wave_max_u32(hi);
      unsigned rk = (unsigned)tkey & 0x3FFFFFFu;
      unsigned long long msk = __ballot(hi == M);
      unsigned lo;
      if (__popcll(msk) == 1) {          // sole owner (the ~always case)
        int ln = (int)__builtin_ctzll(msk);
        lo = (unsigned)__builtin_amdgcn_readlane((int)rk, ln);
      } else {                           // exact d2 tie: max RK = min orig
        lo = wave_max_u32((hi == M) ? rk : 0u);
      }
      wkey = ((unsigned long long)M << 26) | lo;
    }
    if ((tid & 63) == 0) atomicMax(&slot3[m % 3], wkey);
    __syncthreads();
    sidx = (unsigned)(slot3[m % 3] & 0x1FFFull);
  }
  if (tid == 0) winb[MPER-1] = (unsigned short)sidx;
  __syncthreads();
  // reconstruct pos_out from LDS
  for (int e = tid; e < MPER; e += FPS_T) {
    unsigned s = winb[e];
    qo[e*3+0] = Xs[s]; qo[e*3+1] = Ys[s]; qo[e*3+2] = Zs[s];
  }
}

// ------------------------------------------------- K2: radius + top-K select
// One wave per centroid, cell-culled (+-2 cells, exact since R=0.2<2*0.125).
// 25 (ix,iy) segments of contiguous iz-runs; bounds prefetched lane-parallel.
// Candidates via ballot-prefix; (H=d2,L=orig) 512-bitonic -> bitwise-equal
// selection + lower-index tie-break to jax top_k.
#define SCAP 512
__global__ __launch_bounds__(256) void k_radius(const float* __restrict__ pos,
    float* __restrict__ dout, unsigned short* __restrict__ nbr,
    int* __restrict__ cnt)
{
  __shared__ unsigned candH[4][SCAP];
  __shared__ unsigned candL[4][SCAP];
  const int wid = threadIdx.x >> 6, lane = threadIdx.x & 63;
  const int m = blockIdx.x * 4 + wid;
  const int b = m >> 12;
  const float* scrb = dout + (size_t)b * SSTR;
  const float* SX = scrb;
  const float* SY = scrb + 8192;
  const float* SZ = scrb + 16384;
  const unsigned short* SO = (const unsigned short*)(scrb + 24576);
  const unsigned* CS = (const unsigned*)(scrb + 28672);
  const float* q = dout + POSOUT_OFF + (size_t)m * 3;
  const float qx = q[0], qy = q[1], qz = q[2];
  const int ixc = min(7, (int)(qx * 8.0f));
  const int iyc = min(7, (int)(qy * 8.0f));
  const int izc = min(7, (int)(qz * 8.0f));
  const int izlo = max(izc-2, 0), izhi = min(izc+2, 7);
  unsigned s0v = 0u, s1v = 0u;
  {
    int ix = ixc + lane / 5 - 2;
    int iy = iyc + lane % 5 - 2;
    if (lane < 25 && ix >= 0 && ix < 8 && iy >= 0 && iy < 8) {
      int cb = (ix << 6) | (iy << 3);
      s0v = CS[cb + izlo];
      s1v = CS[cb + izhi + 1];
    }
  }
  unsigned cw = 0;
  for (int seg = 0; seg < 25; ++seg) {
    unsigned s0 = (unsigned)__builtin_amdgcn_readlane((int)s0v, seg);
    unsigned s1 = (unsigned)__builtin_amdgcn_readlane((int)s1v, seg);
    for (unsigned i0 = s0; i0 < s1; i0 += 64) {
      unsigned i = i0 + (unsigned)lane;     // OOB lanes read harmless bytes
      float dx = __fsub_rn(qx, SX[i]);
      float dy = __fsub_rn(qy, SY[i]);
      float dz = __fsub_rn(qz, SZ[i]);
      float d2 = __fadd_rn(__fadd_rn(__fmul_rn(dx,dx), __fmul_rn(dy,dy)),
                           __fmul_rn(dz,dz));
      bool in = (i < s1) && (d2 <= R2C);
      unsigned long long mk = __ballot(in);
      unsigned pre = (unsigned)__popcll(mk & ((1ull << lane) - 1ull));
      if (in) {
        unsigned slot = cw + pre;
        if (slot < SCAP) {
          candH[wid][slot] = __float_as_uint(d2);
          candL[wid][slot] = (unsigned)SO[i];
        }
      }
      cw += (unsigned)__popcll(mk);
    }
  }
  if (cw > SCAP) cw = SCAP;
  for (int s = (int)cw + lane; s < SCAP; s += 64) {
    candH[wid][s] = 0xFFFFFFFFu; candL[wid][s] = 0xFFFFFFFFu;
  }
  __syncthreads();
  for (int k = 2; k <= SCAP; k <<= 1) {
    for (int j = k >> 1; j > 0; j >>= 1) {
#pragma unroll
      for (int s = 0; s < SCAP/128; ++s) {
        int t = lane + (s << 6);
        int e = ((t & ~(j-1)) << 1) | (t & (j-1));
        int p = e | j;
        unsigned aH = candH[wid][e], aL = candL[wid][e];
        unsigned cH = candH[wid][p], cL = candL[wid][p];
        bool agt = (aH > cH) || (aH == cH && aL > cL);
        bool asc = ((e & k) == 0);
        bool sw = asc ? agt : !agt && (aH != cH || aL != cL);
        if (sw) {
          candH[wid][e] = cH; candL[wid][e] = cL;
          candH[wid][p] = aH; candL[wid][p] = aL;
        }
      }
      __syncthreads();
    }
  }
  int kk = (int)cw; if (kk > KNB) kk = KNB;
  nbr[(size_t)m*KNB + lane] =
    (lane < kk) ? (unsigned short)(candL[wid][lane] & 0xFFFFu)
                : (unsigned short)0;
  if (lane == 0) {
    cnt[m] = kk;
    dout[BATCH_OFF + m] = (float)b;   // batch_out (buffer read as f32)
  }
}

// ---------------------------------- K3a: conv using precomp (ws-size gated)
// Gather hp rows (h1 partial sums) -> h1T in LDS; fuse rel@W1[64:67] + b1 +
// relu (fmaf order 64,65,66 then +b1: bitwise == legacy); stage2 packed
// v_pk_fma. LDS ~28KB.
__global__ __launch_bounds__(128) void k_conv2(
    const float* __restrict__ hp, const float* __restrict__ pos,
    const float* __restrict__ W1, const float* __restrict__ b1,
    const float* __restrict__ W2, const float* __restrict__ b2,
    const unsigned short* __restrict__ nbr, const int* __restrict__ cntp,
    float* __restrict__ dout)
{
  __shared__ __align__(16) float bufA[68*68];   // h1T rows 0..63, relT 64..66
  __shared__ __align__(16) float bufB[16*136];  // W2 chunk (stride 136)
  __shared__ float w1p[3*64];
  __shared__ unsigned short nbr_s[64];
  __shared__ float qv[3];
  __shared__ int cnt_s;
  const int t = threadIdx.x;
  const int m = blockIdx.x;
  const int b = m >> 12;
  if (t < 64) nbr_s[t] = nbr[(size_t)m*KNB + t];
  else if (t == 64) cnt_s = cntp[m];
  else if (t >= 65 && t < 68) qv[t-65] = dout[POSOUT_OFF + (size_t)m*3 + (t-65)];
  for (int e = t; e < 192; e += 128) w1p[e] = W1[64*64 + e];
  __syncthreads();
  {                                   // gather hp rows -> h1T rows 0..63
    const int h = t & 63, jj = t >> 6;
    const size_t hb = (size_t)b * NPER * 64;
    for (int j0 = 0; j0 < 64; j0 += 2) {
      int j = j0 + jj;
      int r = nbr_s[j];
      bufA[h*68 + j] = hp[hb + (size_t)r*64 + h];
    }
  }
  {                                   // rel -> rows 64..66
    const size_t pbb = (size_t)b * NPER * 3;
    for (int e = t; e < 192; e += 128) {
      int j = e & 63, d = e >> 6;
      int r = nbr_s[j];
      bufA[(64+d)*68 + j] = pos[pbb + (size_t)r*3 + d] - qv[d];
    }
  }
  __syncthreads();
  // fuse: h1T[h][j] = relu(h1T + rel@w1p + b1)  (fmaf order 64,65,66, +b1)
  for (int e = t; e < 64*64; e += 128) {
    int h = e >> 6, j = e & 63;
    float v = bufA[h*68 + j];
    v = fmaf(bufA[64*68 + j], w1p[h],       v);
    v = fmaf(bufA[65*68 + j], w1p[64 + h],  v);
    v = fmaf(bufA[66*68 + j], w1p[128 + h], v);
    bufA[h*68 + j] = fmaxf(v + b1[h], 0.0f);
  }
  const int jg = t & 7, hg = t >> 3;
  const int j0 = jg << 3;
  const int c0 = hg << 3;             // stage2: 8j x 8c packed pairs
  v2f acc2p[8][4];                    // [c][jpair]
#pragma unroll
  for (int c = 0; c < 8; ++c)
#pragma unroll
    for (int jp = 0; jp < 4; ++jp) acc2p[c][jp] = (v2f){0.0f, 0.0f};
  for (int hc = 0; hc < 64; hc += 16) {
    __syncthreads();                  // h1T ready / prior chunk consumed
    for (int e = t; e < 16*128; e += 128) {
      int hh = e >> 7, c = e & 127;
      bufB[hh*136 + c] = W2[(size_t)(hc+hh)*128 + c];
    }
    __syncthreads();
#pragma unroll
    for (int h = 0; h < 16; ++h) {
      const float4 ja = *(const float4*)&bufA[(hc+h)*68 + j0];
      const float4 jb = *(const float4*)&bufA[(hc+h)*68 + j0 + 4];
      const float4 wa = *(const float4*)&bufB[h*136 + c0];
      const float4 wb = *(const float4*)&bufB[h*136 + c0 + 4];
      const v2f hj[4] = {{ja.x, ja.y}, {ja.z, ja.w}, {jb.x, jb.y}, {jb.z, jb.w}};
      const float wv[8] = {wa.x, wa.y, wa.z, wa.w, wb.x, wb.y, wb.z, wb.w};
#pragma unroll
      for (int c = 0; c < 8; ++c) {
        const v2f w2 = {wv[c], wv[c]};
#pragma unroll
        for (int jp = 0; jp < 4; ++jp)
          acc2p[c][jp] += w2 * hj[jp];          // v_pk_fma_f32
      }
    }
  }
  const int cntv = cnt_s;
  const float4 b2a = *(const float4*)&b2[c0];
  const float4 b2b = *(const float4*)&b2[c0 + 4];
  const float bv2[8] = {b2a.x, b2a.y, b2a.z, b2a.w, b2b.x, b2b.y, b2b.z, b2b.w};
  float best[8];
#pragma unroll
  for (int c = 0; c < 8; ++c) {
    float v = -3.402823466e+38f;
#pragma unroll
    for (int jp = 0; jp < 4; ++jp) {
      float h0v = fmaxf(acc2p[c][jp].x + bv2[c], 0.0f);
      float h1v = fmaxf(acc2p[c][jp].y + bv2[c], 0.0f);
      v = (j0 + 2*jp     < cntv) ? fmaxf(v, h0v) : v;
      v = (j0 + 2*jp + 1 < cntv) ? fmaxf(v, h1v) : v;
    }
    best[c] = v;
  }
#pragma unroll
  for (int off = 1; off < 8; off <<= 1)
#pragma unroll
    for (int c = 0; c < 8; ++c)
      best[c] = fmaxf(best[c], __shfl_xor(best[c], off));
  if (jg == 0) {
    float4 o0 = {best[0], best[1], best[2], best[3]};
    float4 o1 = {best[4], best[5], best[6], best[7]};
    *(float4*)&dout[(size_t)m*128 + c0] = o0;
    *(float4*)&dout[(size_t)m*128 + c0 + 4] = o1;
  }
}

// --------------------------------------------- K3b: legacy conv (fallback)
__global__ __launch_bounds__(128) void k_conv(
    const float* __restrict__ x, const float* __restrict__ pos,
    const float* __restrict__ W1, const float* __restrict__ b1,
    const float* __restrict__ W2, const float* __restrict__ b2,
    const unsigned short* __restrict__ nbr, const int* __restrict__ cntp,
    float* __restrict__ dout)
{
  __shared__ __align__(16) float bufA[68*68];
  __shared__ __align__(16) float bufB[68*68];
  __shared__ unsigned short nbr_s[64];
  __shared__ float qv[3];
  __shared__ int cnt_s;
  const int t = threadIdx.x;
  const int m = blockIdx.x;
  const int b = m >> 12;
  if (t < 64) nbr_s[t] = nbr[(size_t)m*KNB + t];
  else if (t == 64) cnt_s = cntp[m];
  else if (t >= 65 && t < 68) qv[t-65] = dout[POSOUT_OFF + (size_t)m*3 + (t-65)];
  for (int e = t; e < 67*64; e += 128) {
    int ch = e >> 6, h = e & 63;
    bufB[ch*68 + h] = W1[e];
  }
  __syncthreads();
  {
    const int ch = t & 63, jj = t >> 6;
    const size_t xb = (size_t)b * NPER * CIN;
    for (int j0 = 0; j0 < 64; j0 += 2) {
      int j = j0 + jj;
      int r = nbr_s[j];
      bufA[ch*68 + j] = x[xb + (size_t)r*CIN + ch];
    }
  }
  {
    const size_t pbb = (size_t)b * NPER * 3;
    for (int e = t; e < 192; e += 128) {
      int j = e & 63, d = e >> 6;
      int r = nbr_s[j];
      bufA[(64+d)*68 + j] = pos[pbb + (size_t)r*3 + d] - qv[d];
    }
  }
  __syncthreads();
  const int jg = t & 7, hg = t >> 3;
  const int j0 = jg << 3;
  const int h0 = hg << 2;
  v2f accp[4][4];
#pragma unroll
  for (int hh = 0; hh < 4; ++hh)
#pragma unroll
    for (int jp = 0; jp < 4; ++jp) accp[hh][jp] = (v2f){0.0f, 0.0f};
  for (int ch = 0; ch < 67; ++ch) {
    const float4 fa = *(const float4*)&bufA[ch*68 + j0];
    const float4 fb = *(const float4*)&bufA[ch*68 + j0 + 4];
    const float4 w  = *(const float4*)&bufB[ch*68 + h0];
    const v2f fj[4] = {{fa.x, fa.y}, {fa.z, fa.w}, {fb.x, fb.y}, {fb.z, fb.w}};
    const float ws4[4] = {w.x, w.y, w.z, w.w};
#pragma unroll
    for (int hh = 0; hh < 4; ++hh) {
      const v2f wv2 = {ws4[hh], ws4[hh]};
#pragma unroll
      for (int jp = 0; jp < 4; ++jp)
        accp[hh][jp] += wv2 * fj[jp];
    }
  }
  __syncthreads();
  {
    const float4 bb = *(const float4*)&b1[h0];
    const float bv[4] = {bb.x, bb.y, bb.z, bb.w};
#pragma unroll
    for (int hh = 0; hh < 4; ++hh) {
      float4 o0, o1;
      o0.x = fmaxf(accp[hh][0].x + bv[hh], 0.0f);
      o0.y = fmaxf(accp[hh][0].y + bv[hh], 0.0f);
      o0.z = fmaxf(accp[hh][1].x + bv[hh], 0.0f);
      o0.w = fmaxf(accp[hh][1].y + bv[hh], 0.0f);
      o1.x = fmaxf(accp[hh][2].x + bv[hh], 0.0f);
      o1.y = fmaxf(accp[hh][2].y + bv[hh], 0.0f);
      o1.z = fmaxf(accp[hh][3].x + bv[hh], 0.0f);
      o1.w = fmaxf(accp[hh][3].y + bv[hh], 0.0f);
      *(float4*)&bufA[(h0+hh)*68 + j0] = o0;
      *(float4*)&bufA[(h0+hh)*68 + j0 + 4] = o1;
    }
  }
  const int c0 = hg << 3;
  v2f acc2p[8][4];
#pragma unroll
  for (int c = 0; c < 8; ++c)
#pragma unroll
    for (int jp = 0; jp < 4; ++jp) acc2p[c][jp] = (v2f){0.0f, 0.0f};
  for (int hc = 0; hc < 64; hc += 16) {
    __syncthreads();
    for (int e = t; e < 16*128; e += 128) {
      int hh = e >> 7, c = e & 127;
      bufB[hh*136 + c] = W2[(size_t)(hc+hh)*128 + c];
    }
    __syncthreads();
#pragma unroll
    for (int h = 0; h < 16; ++h) {
      const float4 ja = *(const float4*)&bufA[(hc+h)*68 + j0];
      const float4 jb = *(const float4*)&bufA[(hc+h)*68 + j0 + 4];
      const float4 wa = *(const float4*)&bufB[h*136 + c0];
      const float4 wb = *(const float4*)&bufB[h*136 + c0 + 4];
      const v2f hj[4] = {{ja.x, ja.y}, {ja.z, ja.w}, {jb.x, jb.y}, {jb.z, jb.w}};
      const float wv[8] = {wa.x, wa.y, wa.z, wa.w, wb.x, wb.y, wb.z, wb.w};
#pragma unroll
      for (int c = 0; c < 8; ++c) {
        const v2f w2 = {wv[c], wv[c]};
#pragma unroll
        for (int jp = 0; jp < 4; ++jp)
          acc2p[c][jp] += w2 * hj[jp];
      }
    }
  }
  const int cntv = cnt_s;
  const float4 b2a = *(const float4*)&b2[c0];
  const float4 b2b = *(const float4*)&b2[c0 + 4];
  const float bv2[8] = {b2a.x, b2a.y, b2a.z, b2a.w, b2b.x, b2b.y, b2b.z, b2b.w};
  float best[8];
#pragma unroll
  for (int c = 0; c < 8; ++c) {
    float v = -3.402823466e+38f;
#pragma unroll
    for (int jp = 0; jp < 4; ++jp) {
      float h0v = fmaxf(acc2p[c][jp].x + bv2[c], 0.0f);
      float h1v = fmaxf(acc2p[c][jp].y + bv2[c], 0.0f);
      v = (j0 + 2*jp     < cntv) ? fmaxf(v, h0v) : v;
      v = (j0 + 2*jp + 1 < cntv) ? fmaxf(v, h1v) : v;
    }
    best[c] = v;
  }
#pragma unroll
  for (int off = 1; off < 8; off <<= 1)
#pragma unroll
    for (int c = 0; c < 8; ++c)
      best[c] = fmaxf(best[c], __shfl_xor(best[c], off));
  if (jg == 0) {
    float4 o0 = {best[0], best[1], best[2], best[3]};
    float4 o1 = {best[4], best[5], best[6], best[7]};
    *(float4*)&dout[(size_t)m*128 + c0] = o0;
    *(float4*)&dout[(size_t)m*128 + c0 + 4] = o1;
  }
}

extern "C" void kernel_launch(void* const* d_in, const int* in_sizes, int n_in,
                              void* d_out, int out_size, void* d_ws, size_t ws_size,
                              hipStream_t stream) {
  const float* x   = (const float*)d_in[0];
  const float* pos = (const float*)d_in[1];
  // d_in[2] = batch (layout known statically, unused)
  const float* W1  = (const float*)d_in[3];
  const float* b1  = (const float*)d_in[4];
  const float* W2  = (const float*)d_in[5];
  const float* b2  = (const float*)d_in[6];
  float* dout = (float*)d_out;
  unsigned short* nbr = (unsigned short*)d_ws;
  int* cnt = (int*)((char*)d_ws + (size_t)MTOT*KNB*2);
  float* hp = (float*)((char*)d_ws + PRE_OFF);
  const bool use_pre = (ws_size >= PRE_OFF + PRE_BYTES);  // constant per run

  // R15 structure (banked best): k_pre fused into the k_fps dispatch as
  // burst blocks NB..NB+511; split k_radius -> k_conv2 tail.
  const int grid = use_pre ? (NB + NB*NPER/64) : NB;
  hipLaunchKernelGGL(k_fps,    dim3(grid),   dim3(FPS_T), FPS_LDS, stream,
                     pos, dout, x, W1, hp);
  hipLaunchKernelGGL(k_radius, dim3(MTOT/4), dim3(256),   0, stream, pos, dout, nbr, cnt);
  if (use_pre) {
    hipLaunchKernelGGL(k_conv2, dim3(MTOT),       dim3(128), 0, stream,
                       hp, pos, W1, b1, W2, b2, nbr, cnt, dout);
  } else {
    hipLaunchKernelGGL(k_conv,  dim3(MTOT),       dim3(128), 0, stream,
                       x, pos, W1, b1, W2, b2, nbr, cnt, dout);
  }
}